// Round 1
// baseline (459.065 us; speedup 1.0000x reference)
//
#include <hip/hip_runtime.h>

// SGConv (k=1) + Linear, fused pipeline:
//   1) deg[dst]++            (histogram, int atomics)
//   2) exclusive scan(deg)   (single block)
//   3) xs = x * rsqrt(max(deg,1)) ; norm[] saved
//   4) counting-sort edges by dst (atomic binning)
//   5) h2[n] = norm[n] * sum_{e in bin(n)} xs[src[e]]   (wave per node, no atomics)
//   6) out = relu(relu(h2 @ Wc^T + bc) @ Wl^T + bl)     (fused double GEMM, fp32 VALU)

#define D 128

__global__ void degree_kernel(const int* __restrict__ dst, int* __restrict__ deg, int E) {
    int e = blockIdx.x * blockDim.x + threadIdx.x;
    if (e < E) atomicAdd(&deg[dst[e]], 1);
}

// single-block exclusive scan over N degrees -> row_start[0..N], cursor copy
__global__ __launch_bounds__(256) void scan_kernel(const int* __restrict__ deg,
                                                   int* __restrict__ row_start,
                                                   int* __restrict__ cursor, int N) {
    __shared__ int sums[256];
    int tid = threadIdx.x;
    int chunk = (N + 255) >> 8;
    int lo = min(tid * chunk, N);
    int hi = min(lo + chunk, N);
    int s = 0;
    for (int i = lo; i < hi; ++i) s += deg[i];
    sums[tid] = s;
    __syncthreads();
    // Hillis-Steele inclusive scan over 256 partials
    for (int off = 1; off < 256; off <<= 1) {
        int v = (tid >= off) ? sums[tid - off] : 0;
        __syncthreads();
        sums[tid] += v;
        __syncthreads();
    }
    int run = (tid == 0) ? 0 : sums[tid - 1];
    for (int i = lo; i < hi; ++i) {
        row_start[i] = run;
        cursor[i] = run;
        run += deg[i];
    }
    if (tid == 255) row_start[N] = run;
}

// xs = x * rsqrt(max(deg,1)); also save norm per row. float4 over N*32.
__global__ void scale_kernel(const float* __restrict__ x, const int* __restrict__ deg,
                             float* __restrict__ xs, float* __restrict__ norm, int N) {
    int idx = blockIdx.x * blockDim.x + threadIdx.x;
    int total = N * (D / 4);
    if (idx >= total) return;
    int row = idx >> 5;  // D/4 == 32
    float nrm = rsqrtf(fmaxf((float)deg[row], 1.0f));
    if ((idx & 31) == 0) norm[row] = nrm;
    float4 v = ((const float4*)x)[idx];
    v.x *= nrm; v.y *= nrm; v.z *= nrm; v.w *= nrm;
    ((float4*)xs)[idx] = v;
}

__global__ void binning_kernel(const int* __restrict__ src, const int* __restrict__ dst,
                               int* __restrict__ cursor, int* __restrict__ sorted_src, int E) {
    int e = blockIdx.x * blockDim.x + threadIdx.x;
    if (e < E) {
        int d = dst[e];
        int p = atomicAdd(&cursor[d], 1);
        sorted_src[p] = src[e];
    }
}

// wave per destination node: h2[n] = norm[n] * sum over its edges of xs[src]
__global__ __launch_bounds__(256) void aggregate_kernel(
    const float* __restrict__ xs, const int* __restrict__ sorted_src,
    const int* __restrict__ row_start, const float* __restrict__ norm,
    float* __restrict__ h2, int N) {
    int wave = (int)((blockIdx.x * blockDim.x + threadIdx.x) >> 6);
    int lane = threadIdx.x & 63;
    if (wave >= N) return;
    int s = row_start[wave];
    int t = row_start[wave + 1];
    float2 acc = {0.0f, 0.0f};
    for (int base = s; base < t; base += 64) {
        int cnt = min(64, t - base);
        int my = (lane < cnt) ? sorted_src[base + lane] : 0;
        int j = 0;
        for (; j + 1 < cnt; j += 2) {  // 2 outstanding row loads to hide L2/L3 latency
            int s0 = __shfl(my, j, 64);
            int s1 = __shfl(my, j + 1, 64);
            float2 v0 = *(const float2*)(xs + (size_t)s0 * D + 2 * lane);
            float2 v1 = *(const float2*)(xs + (size_t)s1 * D + 2 * lane);
            acc.x += v0.x + v1.x;
            acc.y += v0.y + v1.y;
        }
        if (j < cnt) {
            int s0 = __shfl(my, j, 64);
            float2 v0 = *(const float2*)(xs + (size_t)s0 * D + 2 * lane);
            acc.x += v0.x;
            acc.y += v0.y;
        }
    }
    float nrm = norm[wave];
    float2 o = {acc.x * nrm, acc.y * nrm};
    *(float2*)(h2 + (size_t)wave * D + 2 * lane) = o;
}

// fused: out = relu(relu(h2 @ Wc^T + bc) @ Wl^T + bl)
// 64 rows per block, 512 threads; W transposed into LDS (pad 129 -> conflict-free b128 reads)
#define MLP_ROWS 64
#define FMA4(ACC, S, W) \
    ACC.x = fmaf(S, W.x, ACC.x); ACC.y = fmaf(S, W.y, ACC.y); \
    ACC.z = fmaf(S, W.z, ACC.z); ACC.w = fmaf(S, W.w, ACC.w)
#define RELU4(A) \
    A.x = fmaxf(A.x, 0.0f); A.y = fmaxf(A.y, 0.0f); \
    A.z = fmaxf(A.z, 0.0f); A.w = fmaxf(A.w, 0.0f)

__global__ __launch_bounds__(512) void mlp_kernel(
    const float* __restrict__ h2, const float* __restrict__ wc, const float* __restrict__ bc,
    const float* __restrict__ wl, const float* __restrict__ bl,
    float* __restrict__ out, int N) {
    __shared__ float wt[128 * 129];       // W^T, padded: wt[k*129 + o]
    __shared__ float ht[MLP_ROWS * 128];  // h tile, stride 128
    int tid = threadIdx.x;
    int row0 = blockIdx.x * MLP_ROWS;
    int cg = tid & 31, rg = tid >> 5;     // 32 col-groups x 16 row-groups
    int o0 = cg << 2, r0 = rg << 2;       // 4 cols x 4 rows per thread

    // stage Wc transposed (coalesced global float4; scalar LDS writes)
    for (int i = 0; i < 8; ++i) {
        int flat = (tid << 2) + (i << 11);
        float4 w4 = *(const float4*)(wc + flat);
        int o = flat >> 7, k = flat & 127;
        wt[(k + 0) * 129 + o] = w4.x;
        wt[(k + 1) * 129 + o] = w4.y;
        wt[(k + 2) * 129 + o] = w4.z;
        wt[(k + 3) * 129 + o] = w4.w;
    }
    // stage h2 tile (zero-pad tail rows)
    for (int i = 0; i < 4; ++i) {
        int flat = (tid << 2) + (i << 11);
        int r = flat >> 7;
        int grow = row0 + r;
        float4 v = make_float4(0.f, 0.f, 0.f, 0.f);
        if (grow < N) v = *(const float4*)(h2 + (size_t)grow * D + (flat & 127));
        *(float4*)(ht + flat) = v;
    }
    __syncthreads();

    float4 acc0, acc1, acc2, acc3;
    {   // layer 1
        float4 b4 = *(const float4*)(bc + o0);
        acc0 = b4; acc1 = b4; acc2 = b4; acc3 = b4;
        for (int k = 0; k < 128; k += 4) {
            float4 w0 = *(float4*)(wt + (k + 0) * 129 + o0);
            float4 w1 = *(float4*)(wt + (k + 1) * 129 + o0);
            float4 w2 = *(float4*)(wt + (k + 2) * 129 + o0);
            float4 w3 = *(float4*)(wt + (k + 3) * 129 + o0);
            float4 h;
            h = *(float4*)(ht + (r0 + 0) * 128 + k);
            FMA4(acc0, h.x, w0); FMA4(acc0, h.y, w1); FMA4(acc0, h.z, w2); FMA4(acc0, h.w, w3);
            h = *(float4*)(ht + (r0 + 1) * 128 + k);
            FMA4(acc1, h.x, w0); FMA4(acc1, h.y, w1); FMA4(acc1, h.z, w2); FMA4(acc1, h.w, w3);
            h = *(float4*)(ht + (r0 + 2) * 128 + k);
            FMA4(acc2, h.x, w0); FMA4(acc2, h.y, w1); FMA4(acc2, h.z, w2); FMA4(acc2, h.w, w3);
            h = *(float4*)(ht + (r0 + 3) * 128 + k);
            FMA4(acc3, h.x, w0); FMA4(acc3, h.y, w1); FMA4(acc3, h.z, w2); FMA4(acc3, h.w, w3);
        }
        RELU4(acc0); RELU4(acc1); RELU4(acc2); RELU4(acc3);
    }
    __syncthreads();  // all reads of ht/wt complete before overwrite

    // write h3 into ht; stage Wl transposed
    *(float4*)(ht + (r0 + 0) * 128 + o0) = acc0;
    *(float4*)(ht + (r0 + 1) * 128 + o0) = acc1;
    *(float4*)(ht + (r0 + 2) * 128 + o0) = acc2;
    *(float4*)(ht + (r0 + 3) * 128 + o0) = acc3;
    for (int i = 0; i < 8; ++i) {
        int flat = (tid << 2) + (i << 11);
        float4 w4 = *(const float4*)(wl + flat);
        int o = flat >> 7, k = flat & 127;
        wt[(k + 0) * 129 + o] = w4.x;
        wt[(k + 1) * 129 + o] = w4.y;
        wt[(k + 2) * 129 + o] = w4.z;
        wt[(k + 3) * 129 + o] = w4.w;
    }
    __syncthreads();

    {   // layer 2
        float4 b4 = *(const float4*)(bl + o0);
        acc0 = b4; acc1 = b4; acc2 = b4; acc3 = b4;
        for (int k = 0; k < 128; k += 4) {
            float4 w0 = *(float4*)(wt + (k + 0) * 129 + o0);
            float4 w1 = *(float4*)(wt + (k + 1) * 129 + o0);
            float4 w2 = *(float4*)(wt + (k + 2) * 129 + o0);
            float4 w3 = *(float4*)(wt + (k + 3) * 129 + o0);
            float4 h;
            h = *(float4*)(ht + (r0 + 0) * 128 + k);
            FMA4(acc0, h.x, w0); FMA4(acc0, h.y, w1); FMA4(acc0, h.z, w2); FMA4(acc0, h.w, w3);
            h = *(float4*)(ht + (r0 + 1) * 128 + k);
            FMA4(acc1, h.x, w0); FMA4(acc1, h.y, w1); FMA4(acc1, h.z, w2); FMA4(acc1, h.w, w3);
            h = *(float4*)(ht + (r0 + 2) * 128 + k);
            FMA4(acc2, h.x, w0); FMA4(acc2, h.y, w1); FMA4(acc2, h.z, w2); FMA4(acc2, h.w, w3);
            h = *(float4*)(ht + (r0 + 3) * 128 + k);
            FMA4(acc3, h.x, w0); FMA4(acc3, h.y, w1); FMA4(acc3, h.z, w2); FMA4(acc3, h.w, w3);
        }
        RELU4(acc0); RELU4(acc1); RELU4(acc2); RELU4(acc3);
    }
    int grow = row0 + r0;
    if (grow + 0 < N) *(float4*)(out + (size_t)(grow + 0) * D + o0) = acc0;
    if (grow + 1 < N) *(float4*)(out + (size_t)(grow + 1) * D + o0) = acc1;
    if (grow + 2 < N) *(float4*)(out + (size_t)(grow + 2) * D + o0) = acc2;
    if (grow + 3 < N) *(float4*)(out + (size_t)(grow + 3) * D + o0) = acc3;
}

extern "C" void kernel_launch(void* const* d_in, const int* in_sizes, int n_in,
                              void* d_out, int out_size, void* d_ws, size_t ws_size,
                              hipStream_t stream) {
    const float* x      = (const float*)d_in[0];
    const int*   src    = (const int*)d_in[1];
    const int*   dst    = (const int*)d_in[2];
    const float* wc     = (const float*)d_in[3];
    const float* bc     = (const float*)d_in[4];
    const float* wl     = (const float*)d_in[5];
    const float* bl     = (const float*)d_in[6];
    float* out = (float*)d_out;

    int N = in_sizes[0] / D;
    int E = in_sizes[1];

    // workspace carve-up (256B aligned)
    size_t off = 0;
    auto carve = [&](size_t bytes) -> void* {
        void* p = (char*)d_ws + off;
        off += (bytes + 255) & ~(size_t)255;
        return p;
    };
    float* xs        = (float*)carve((size_t)N * D * 4);
    float* h2        = (float*)carve((size_t)N * D * 4);
    int*   deg       = (int*)carve((size_t)N * 4);
    int*   row_start = (int*)carve((size_t)(N + 1) * 4);
    int*   cursor    = (int*)carve((size_t)N * 4);
    float* norm      = (float*)carve((size_t)N * 4);
    int*   sorted    = (int*)carve((size_t)E * 4);
    (void)ws_size;

    hipMemsetAsync(deg, 0, (size_t)N * 4, stream);

    degree_kernel<<<(E + 255) / 256, 256, 0, stream>>>(dst, deg, E);
    scan_kernel<<<1, 256, 0, stream>>>(deg, row_start, cursor, N);
    {
        int total = N * (D / 4);
        scale_kernel<<<(total + 255) / 256, 256, 0, stream>>>(x, deg, xs, norm, N);
    }
    binning_kernel<<<(E + 255) / 256, 256, 0, stream>>>(src, dst, cursor, sorted, E);
    aggregate_kernel<<<(N + 3) / 4, 256, 0, stream>>>(xs, sorted, row_start, norm, h2, N);
    mlp_kernel<<<(N + MLP_ROWS - 1) / MLP_ROWS, 512, 0, stream>>>(h2, wc, bc, wl, bl, out, N);
}

// Round 2
// 341.731 us; speedup vs baseline: 1.3434x; 1.3434x over previous
//
#include <hip/hip_runtime.h>

// SGConv (k=1) + Linear, fused pipeline:
//   1) deg[dst]++                   (histogram, int atomics, int4 edge reads)
//   2) exclusive scan(deg)          (3-phase multi-block scan)
//   3) xs = x * rsqrt(max(deg,1)) ; norm[] saved
//   4) counting-sort edges by dst   (atomic binning, int4 edge reads)
//   5) h2[n] = norm[n] * sum_{e in bin(n)} xs[src[e]]   (wave per node, no atomics)
//   6) out = relu(relu(h2 @ Wc^T + bc) @ Wl^T + bl)     (fused double GEMM, fp32 VALU)

#define D 128
#define SCAN_TILE 1024  // 256 threads * 4 elements

__global__ void degree_kernel(const int* __restrict__ dst, int* __restrict__ deg, int E) {
    int i = (blockIdx.x * blockDim.x + threadIdx.x) << 2;
    if (i + 3 < E) {
        int4 d = *(const int4*)(dst + i);
        atomicAdd(&deg[d.x], 1);
        atomicAdd(&deg[d.y], 1);
        atomicAdd(&deg[d.z], 1);
        atomicAdd(&deg[d.w], 1);
    } else {
        for (int j = i; j < E; ++j) atomicAdd(&deg[dst[j]], 1);
    }
}

// ---- 3-phase exclusive scan over deg[0..N) -> row_start[0..N], cursor copy ----
__global__ __launch_bounds__(256) void scan_partial_kernel(const int* __restrict__ deg,
                                                           int* __restrict__ blockSums, int N) {
    int tid = threadIdx.x;
    int base = blockIdx.x * SCAN_TILE + (tid << 2);
    int4 v = make_int4(0, 0, 0, 0);
    if (base + 3 < N) v = *(const int4*)(deg + base);
    else {
        if (base + 0 < N) v.x = deg[base + 0];
        if (base + 1 < N) v.y = deg[base + 1];
        if (base + 2 < N) v.z = deg[base + 2];
        if (base + 3 < N) v.w = deg[base + 3];
    }
    int s = v.x + v.y + v.z + v.w;
    for (int off = 32; off; off >>= 1) s += __shfl_down(s, off, 64);
    __shared__ int ws[4];
    if ((tid & 63) == 0) ws[tid >> 6] = s;
    __syncthreads();
    if (tid == 0) blockSums[blockIdx.x] = ws[0] + ws[1] + ws[2] + ws[3];
}

__global__ __launch_bounds__(256) void scan_blocksums_kernel(int* __restrict__ blockSums, int B) {
    __shared__ int s[256];
    int tid = threadIdx.x;
    int v = (tid < B) ? blockSums[tid] : 0;
    s[tid] = v;
    __syncthreads();
    for (int off = 1; off < 256; off <<= 1) {
        int u = (tid >= off) ? s[tid - off] : 0;
        __syncthreads();
        s[tid] += u;
        __syncthreads();
    }
    if (tid < B) blockSums[tid] = (tid == 0) ? 0 : s[tid - 1];
}

__global__ __launch_bounds__(256) void scan_final_kernel(
    const int* __restrict__ deg, const int* __restrict__ blockSums,
    int* __restrict__ row_start, int* __restrict__ cursor, int N, int E) {
    int tid = threadIdx.x;
    int base = blockIdx.x * SCAN_TILE + (tid << 2);
    int4 v = make_int4(0, 0, 0, 0);
    if (base + 3 < N) v = *(const int4*)(deg + base);
    else {
        if (base + 0 < N) v.x = deg[base + 0];
        if (base + 1 < N) v.y = deg[base + 1];
        if (base + 2 < N) v.z = deg[base + 2];
        if (base + 3 < N) v.w = deg[base + 3];
    }
    int local = v.x + v.y + v.z + v.w;
    int lane = tid & 63, w = tid >> 6;
    int inc = local;
    for (int off = 1; off < 64; off <<= 1) {
        int u = __shfl_up(inc, off, 64);
        if (lane >= off) inc += u;
    }
    __shared__ int wsum[4];
    if (lane == 63) wsum[w] = inc;
    __syncthreads();
    int woff = 0;
    for (int i = 0; i < w; ++i) woff += wsum[i];
    int ex = (inc - local) + woff + blockSums[blockIdx.x];
    int4 rs;
    rs.x = ex;
    rs.y = rs.x + v.x;
    rs.z = rs.y + v.y;
    rs.w = rs.z + v.z;
    if (base + 3 < N) {
        *(int4*)(row_start + base) = rs;
        *(int4*)(cursor + base) = rs;
    } else {
        if (base + 0 < N) { row_start[base + 0] = rs.x; cursor[base + 0] = rs.x; }
        if (base + 1 < N) { row_start[base + 1] = rs.y; cursor[base + 1] = rs.y; }
        if (base + 2 < N) { row_start[base + 2] = rs.z; cursor[base + 2] = rs.z; }
    }
    if (blockIdx.x == 0 && tid == 0) row_start[N] = E;
}

// xs = x * rsqrt(max(deg,1)); also save norm per row. float4 over N*32.
__global__ void scale_kernel(const float* __restrict__ x, const int* __restrict__ deg,
                             float* __restrict__ xs, float* __restrict__ norm, int N) {
    int idx = blockIdx.x * blockDim.x + threadIdx.x;
    int total = N * (D / 4);
    if (idx >= total) return;
    int row = idx >> 5;  // D/4 == 32
    float nrm = rsqrtf(fmaxf((float)deg[row], 1.0f));
    if ((idx & 31) == 0) norm[row] = nrm;
    float4 v = ((const float4*)x)[idx];
    v.x *= nrm; v.y *= nrm; v.z *= nrm; v.w *= nrm;
    ((float4*)xs)[idx] = v;
}

__global__ void binning_kernel(const int* __restrict__ src, const int* __restrict__ dst,
                               int* __restrict__ cursor, int* __restrict__ sorted_src, int E) {
    int i = (blockIdx.x * blockDim.x + threadIdx.x) << 2;
    if (i + 3 < E) {
        int4 d = *(const int4*)(dst + i);
        int4 s = *(const int4*)(src + i);
        sorted_src[atomicAdd(&cursor[d.x], 1)] = s.x;
        sorted_src[atomicAdd(&cursor[d.y], 1)] = s.y;
        sorted_src[atomicAdd(&cursor[d.z], 1)] = s.z;
        sorted_src[atomicAdd(&cursor[d.w], 1)] = s.w;
    } else {
        for (int j = i; j < E; ++j) {
            int p = atomicAdd(&cursor[dst[j]], 1);
            sorted_src[p] = src[j];
        }
    }
}

// wave per destination node: h2[n] = norm[n] * sum over its edges of xs[src]
__global__ __launch_bounds__(256) void aggregate_kernel(
    const float* __restrict__ xs, const int* __restrict__ sorted_src,
    const int* __restrict__ row_start, const float* __restrict__ norm,
    float* __restrict__ h2, int N) {
    int wave = (int)((blockIdx.x * blockDim.x + threadIdx.x) >> 6);
    int lane = threadIdx.x & 63;
    if (wave >= N) return;
    int s = row_start[wave];
    int t = row_start[wave + 1];
    float2 acc = {0.0f, 0.0f};
    for (int base = s; base < t; base += 64) {
        int cnt = min(64, t - base);
        int my = (lane < cnt) ? sorted_src[base + lane] : 0;
        int j = 0;
        for (; j + 3 < cnt; j += 4) {  // 4 outstanding row loads to hide L2/L3 latency
            int s0 = __shfl(my, j + 0, 64);
            int s1 = __shfl(my, j + 1, 64);
            int s2 = __shfl(my, j + 2, 64);
            int s3 = __shfl(my, j + 3, 64);
            float2 v0 = *(const float2*)(xs + (size_t)s0 * D + 2 * lane);
            float2 v1 = *(const float2*)(xs + (size_t)s1 * D + 2 * lane);
            float2 v2 = *(const float2*)(xs + (size_t)s2 * D + 2 * lane);
            float2 v3 = *(const float2*)(xs + (size_t)s3 * D + 2 * lane);
            acc.x += (v0.x + v1.x) + (v2.x + v3.x);
            acc.y += (v0.y + v1.y) + (v2.y + v3.y);
        }
        for (; j < cnt; ++j) {
            int s0 = __shfl(my, j, 64);
            float2 v0 = *(const float2*)(xs + (size_t)s0 * D + 2 * lane);
            acc.x += v0.x;
            acc.y += v0.y;
        }
    }
    float nrm = norm[wave];
    float2 o = {acc.x * nrm, acc.y * nrm};
    *(float2*)(h2 + (size_t)wave * D + 2 * lane) = o;
}

// fused: out = relu(relu(h2 @ Wc^T + bc) @ Wl^T + bl)
// 64 rows per block, 512 threads; W transposed into LDS (pad 129 -> conflict-free b128 reads)
#define MLP_ROWS 64
#define FMA4(ACC, S, W) \
    ACC.x = fmaf(S, W.x, ACC.x); ACC.y = fmaf(S, W.y, ACC.y); \
    ACC.z = fmaf(S, W.z, ACC.z); ACC.w = fmaf(S, W.w, ACC.w)
#define RELU4(A) \
    A.x = fmaxf(A.x, 0.0f); A.y = fmaxf(A.y, 0.0f); \
    A.z = fmaxf(A.z, 0.0f); A.w = fmaxf(A.w, 0.0f)

__global__ __launch_bounds__(512) void mlp_kernel(
    const float* __restrict__ h2, const float* __restrict__ wc, const float* __restrict__ bc,
    const float* __restrict__ wl, const float* __restrict__ bl,
    float* __restrict__ out, int N) {
    __shared__ float wt[128 * 129];       // W^T, padded: wt[k*129 + o]
    __shared__ float ht[MLP_ROWS * 128];  // h tile, stride 128
    int tid = threadIdx.x;
    int row0 = blockIdx.x * MLP_ROWS;
    int cg = tid & 31, rg = tid >> 5;     // 32 col-groups x 16 row-groups
    int o0 = cg << 2, r0 = rg << 2;       // 4 cols x 4 rows per thread

    // stage Wc transposed (coalesced global float4; scalar LDS writes)
    for (int i = 0; i < 8; ++i) {
        int flat = (tid << 2) + (i << 11);
        float4 w4 = *(const float4*)(wc + flat);
        int o = flat >> 7, k = flat & 127;
        wt[(k + 0) * 129 + o] = w4.x;
        wt[(k + 1) * 129 + o] = w4.y;
        wt[(k + 2) * 129 + o] = w4.z;
        wt[(k + 3) * 129 + o] = w4.w;
    }
    // stage h2 tile (zero-pad tail rows)
    for (int i = 0; i < 4; ++i) {
        int flat = (tid << 2) + (i << 11);
        int r = flat >> 7;
        int grow = row0 + r;
        float4 v = make_float4(0.f, 0.f, 0.f, 0.f);
        if (grow < N) v = *(const float4*)(h2 + (size_t)grow * D + (flat & 127));
        *(float4*)(ht + flat) = v;
    }
    __syncthreads();

    float4 acc0, acc1, acc2, acc3;
    {   // layer 1
        float4 b4 = *(const float4*)(bc + o0);
        acc0 = b4; acc1 = b4; acc2 = b4; acc3 = b4;
        for (int k = 0; k < 128; k += 4) {
            float4 w0 = *(float4*)(wt + (k + 0) * 129 + o0);
            float4 w1 = *(float4*)(wt + (k + 1) * 129 + o0);
            float4 w2 = *(float4*)(wt + (k + 2) * 129 + o0);
            float4 w3 = *(float4*)(wt + (k + 3) * 129 + o0);
            float4 h;
            h = *(float4*)(ht + (r0 + 0) * 128 + k);
            FMA4(acc0, h.x, w0); FMA4(acc0, h.y, w1); FMA4(acc0, h.z, w2); FMA4(acc0, h.w, w3);
            h = *(float4*)(ht + (r0 + 1) * 128 + k);
            FMA4(acc1, h.x, w0); FMA4(acc1, h.y, w1); FMA4(acc1, h.z, w2); FMA4(acc1, h.w, w3);
            h = *(float4*)(ht + (r0 + 2) * 128 + k);
            FMA4(acc2, h.x, w0); FMA4(acc2, h.y, w1); FMA4(acc2, h.z, w2); FMA4(acc2, h.w, w3);
            h = *(float4*)(ht + (r0 + 3) * 128 + k);
            FMA4(acc3, h.x, w0); FMA4(acc3, h.y, w1); FMA4(acc3, h.z, w2); FMA4(acc3, h.w, w3);
        }
        RELU4(acc0); RELU4(acc1); RELU4(acc2); RELU4(acc3);
    }
    __syncthreads();  // all reads of ht/wt complete before overwrite

    // write h3 into ht; stage Wl transposed
    *(float4*)(ht + (r0 + 0) * 128 + o0) = acc0;
    *(float4*)(ht + (r0 + 1) * 128 + o0) = acc1;
    *(float4*)(ht + (r0 + 2) * 128 + o0) = acc2;
    *(float4*)(ht + (r0 + 3) * 128 + o0) = acc3;
    for (int i = 0; i < 8; ++i) {
        int flat = (tid << 2) + (i << 11);
        float4 w4 = *(const float4*)(wl + flat);
        int o = flat >> 7, k = flat & 127;
        wt[(k + 0) * 129 + o] = w4.x;
        wt[(k + 1) * 129 + o] = w4.y;
        wt[(k + 2) * 129 + o] = w4.z;
        wt[(k + 3) * 129 + o] = w4.w;
    }
    __syncthreads();

    {   // layer 2
        float4 b4 = *(const float4*)(bl + o0);
        acc0 = b4; acc1 = b4; acc2 = b4; acc3 = b4;
        for (int k = 0; k < 128; k += 4) {
            float4 w0 = *(float4*)(wt + (k + 0) * 129 + o0);
            float4 w1 = *(float4*)(wt + (k + 1) * 129 + o0);
            float4 w2 = *(float4*)(wt + (k + 2) * 129 + o0);
            float4 w3 = *(float4*)(wt + (k + 3) * 129 + o0);
            float4 h;
            h = *(float4*)(ht + (r0 + 0) * 128 + k);
            FMA4(acc0, h.x, w0); FMA4(acc0, h.y, w1); FMA4(acc0, h.z, w2); FMA4(acc0, h.w, w3);
            h = *(float4*)(ht + (r0 + 1) * 128 + k);
            FMA4(acc1, h.x, w0); FMA4(acc1, h.y, w1); FMA4(acc1, h.z, w2); FMA4(acc1, h.w, w3);
            h = *(float4*)(ht + (r0 + 2) * 128 + k);
            FMA4(acc2, h.x, w0); FMA4(acc2, h.y, w1); FMA4(acc2, h.z, w2); FMA4(acc2, h.w, w3);
            h = *(float4*)(ht + (r0 + 3) * 128 + k);
            FMA4(acc3, h.x, w0); FMA4(acc3, h.y, w1); FMA4(acc3, h.z, w2); FMA4(acc3, h.w, w3);
        }
        RELU4(acc0); RELU4(acc1); RELU4(acc2); RELU4(acc3);
    }
    int grow = row0 + r0;
    if (grow + 0 < N) *(float4*)(out + (size_t)(grow + 0) * D + o0) = acc0;
    if (grow + 1 < N) *(float4*)(out + (size_t)(grow + 1) * D + o0) = acc1;
    if (grow + 2 < N) *(float4*)(out + (size_t)(grow + 2) * D + o0) = acc2;
    if (grow + 3 < N) *(float4*)(out + (size_t)(grow + 3) * D + o0) = acc3;
}

extern "C" void kernel_launch(void* const* d_in, const int* in_sizes, int n_in,
                              void* d_out, int out_size, void* d_ws, size_t ws_size,
                              hipStream_t stream) {
    const float* x      = (const float*)d_in[0];
    const int*   src    = (const int*)d_in[1];
    const int*   dst    = (const int*)d_in[2];
    const float* wc     = (const float*)d_in[3];
    const float* bc     = (const float*)d_in[4];
    const float* wl     = (const float*)d_in[5];
    const float* bl     = (const float*)d_in[6];
    float* out = (float*)d_out;

    int N = in_sizes[0] / D;
    int E = in_sizes[1];

    // workspace carve-up (256B aligned)
    size_t off = 0;
    auto carve = [&](size_t bytes) -> void* {
        void* p = (char*)d_ws + off;
        off += (bytes + 255) & ~(size_t)255;
        return p;
    };
    float* xs        = (float*)carve((size_t)N * D * 4);
    float* h2        = (float*)carve((size_t)N * D * 4);
    int*   deg       = (int*)carve((size_t)N * 4);
    int*   row_start = (int*)carve((size_t)(N + 1) * 4);
    int*   cursor    = (int*)carve((size_t)N * 4);
    float* norm      = (float*)carve((size_t)N * 4);
    int*   blockSums = (int*)carve(1024 * 4);
    int*   sorted    = (int*)carve((size_t)E * 4);
    (void)ws_size;

    hipMemsetAsync(deg, 0, (size_t)N * 4, stream);

    int nScanBlocks = (N + SCAN_TILE - 1) / SCAN_TILE;

    degree_kernel<<<(E / 4 + 255) / 256, 256, 0, stream>>>(dst, deg, E);
    scan_partial_kernel<<<nScanBlocks, 256, 0, stream>>>(deg, blockSums, N);
    scan_blocksums_kernel<<<1, 256, 0, stream>>>(blockSums, nScanBlocks);
    scan_final_kernel<<<nScanBlocks, 256, 0, stream>>>(deg, blockSums, row_start, cursor, N, E);
    {
        int total = N * (D / 4);
        scale_kernel<<<(total + 255) / 256, 256, 0, stream>>>(x, deg, xs, norm, N);
    }
    binning_kernel<<<(E / 4 + 255) / 256, 256, 0, stream>>>(src, dst, cursor, sorted, E);
    aggregate_kernel<<<(N + 3) / 4, 256, 0, stream>>>(xs, sorted, row_start, norm, h2, N);
    mlp_kernel<<<(N + MLP_ROWS - 1) / MLP_ROWS, 512, 0, stream>>>(h2, wc, bc, wl, bl, out, N);
}

// Round 4
// 301.249 us; speedup vs baseline: 1.5239x; 1.1344x over previous
//
#include <hip/hip_runtime.h>

// SGConv (k=1) + Linear, fused pipeline:
//   1) deg[dst]++                   (histogram, int atomics, int4 edge reads)
//   2) exclusive scan(deg)          (3-phase multi-block scan; also emits norm[])
//   3) counting-sort edges by dst   (atomic binning, int4 edge reads)
//   4) h2[n] = norm[n] * sum_e norm[src_e] * x[src_e]   (wave per node, no atomics)
//   5) out = relu(relu(h2 @ Wc^T + bc) @ Wl^T + bl)     (fused double GEMM, fp32 VALU)
//      - W read from global (broadcast per 16-lane group, L2-served, no LDS)
//      - h tile in LDS with XOR-swizzled 16B slots (conflict-free all phases)

#define D 128
#define SCAN_TILE 1024  // 256 threads * 4 elements

__global__ void degree_kernel(const int* __restrict__ dst, int* __restrict__ deg, int E) {
    int i = (blockIdx.x * blockDim.x + threadIdx.x) << 2;
    if (i + 3 < E) {
        int4 d = *(const int4*)(dst + i);
        atomicAdd(&deg[d.x], 1);
        atomicAdd(&deg[d.y], 1);
        atomicAdd(&deg[d.z], 1);
        atomicAdd(&deg[d.w], 1);
    } else {
        for (int j = i; j < E; ++j) atomicAdd(&deg[dst[j]], 1);
    }
}

// ---- 3-phase exclusive scan over deg[0..N) -> row_start[0..N], cursor, norm ----
__global__ __launch_bounds__(256) void scan_partial_kernel(const int* __restrict__ deg,
                                                           int* __restrict__ blockSums, int N) {
    int tid = threadIdx.x;
    int base = blockIdx.x * SCAN_TILE + (tid << 2);
    int4 v = make_int4(0, 0, 0, 0);
    if (base + 3 < N) v = *(const int4*)(deg + base);
    else {
        if (base + 0 < N) v.x = deg[base + 0];
        if (base + 1 < N) v.y = deg[base + 1];
        if (base + 2 < N) v.z = deg[base + 2];
        if (base + 3 < N) v.w = deg[base + 3];
    }
    int s = v.x + v.y + v.z + v.w;
    for (int off = 32; off; off >>= 1) s += __shfl_down(s, off, 64);
    __shared__ int ws[4];
    if ((tid & 63) == 0) ws[tid >> 6] = s;
    __syncthreads();
    if (tid == 0) blockSums[blockIdx.x] = ws[0] + ws[1] + ws[2] + ws[3];
}

__global__ __launch_bounds__(256) void scan_blocksums_kernel(int* __restrict__ blockSums, int B) {
    __shared__ int s[256];
    int tid = threadIdx.x;
    int v = (tid < B) ? blockSums[tid] : 0;
    s[tid] = v;
    __syncthreads();
    for (int off = 1; off < 256; off <<= 1) {
        int u = (tid >= off) ? s[tid - off] : 0;
        __syncthreads();
        s[tid] += u;
        __syncthreads();
    }
    if (tid < B) blockSums[tid] = (tid == 0) ? 0 : s[tid - 1];
}

__global__ __launch_bounds__(256) void scan_final_kernel(
    const int* __restrict__ deg, const int* __restrict__ blockSums,
    int* __restrict__ row_start, int* __restrict__ cursor,
    float* __restrict__ norm, int N, int E) {
    int tid = threadIdx.x;
    int base = blockIdx.x * SCAN_TILE + (tid << 2);
    int4 v = make_int4(0, 0, 0, 0);
    if (base + 3 < N) v = *(const int4*)(deg + base);
    else {
        if (base + 0 < N) v.x = deg[base + 0];
        if (base + 1 < N) v.y = deg[base + 1];
        if (base + 2 < N) v.z = deg[base + 2];
        if (base + 3 < N) v.w = deg[base + 3];
    }
    int local = v.x + v.y + v.z + v.w;
    int lane = tid & 63, w = tid >> 6;
    int inc = local;
    for (int off = 1; off < 64; off <<= 1) {
        int u = __shfl_up(inc, off, 64);
        if (lane >= off) inc += u;
    }
    __shared__ int wsum[4];
    if (lane == 63) wsum[w] = inc;
    __syncthreads();
    int woff = 0;
    for (int i = 0; i < w; ++i) woff += wsum[i];
    int ex = (inc - local) + woff + blockSums[blockIdx.x];
    int4 rs;
    rs.x = ex;
    rs.y = rs.x + v.x;
    rs.z = rs.y + v.y;
    rs.w = rs.z + v.z;
    float4 nm;
    nm.x = rsqrtf(fmaxf((float)v.x, 1.0f));
    nm.y = rsqrtf(fmaxf((float)v.y, 1.0f));
    nm.z = rsqrtf(fmaxf((float)v.z, 1.0f));
    nm.w = rsqrtf(fmaxf((float)v.w, 1.0f));
    if (base + 3 < N) {
        *(int4*)(row_start + base) = rs;
        *(int4*)(cursor + base) = rs;
        *(float4*)(norm + base) = nm;
    } else {
        if (base + 0 < N) { row_start[base + 0] = rs.x; cursor[base + 0] = rs.x; norm[base + 0] = nm.x; }
        if (base + 1 < N) { row_start[base + 1] = rs.y; cursor[base + 1] = rs.y; norm[base + 1] = nm.y; }
        if (base + 2 < N) { row_start[base + 2] = rs.z; cursor[base + 2] = rs.z; norm[base + 2] = nm.z; }
    }
    if (blockIdx.x == 0 && tid == 0) row_start[N] = E;
}

__global__ void binning_kernel(const int* __restrict__ src, const int* __restrict__ dst,
                               int* __restrict__ cursor, int* __restrict__ sorted_src, int E) {
    int i = (blockIdx.x * blockDim.x + threadIdx.x) << 2;
    if (i + 3 < E) {
        int4 d = *(const int4*)(dst + i);
        int4 s = *(const int4*)(src + i);
        sorted_src[atomicAdd(&cursor[d.x], 1)] = s.x;
        sorted_src[atomicAdd(&cursor[d.y], 1)] = s.y;
        sorted_src[atomicAdd(&cursor[d.z], 1)] = s.z;
        sorted_src[atomicAdd(&cursor[d.w], 1)] = s.w;
    } else {
        for (int j = i; j < E; ++j) {
            int p = atomicAdd(&cursor[dst[j]], 1);
            sorted_src[p] = src[j];
        }
    }
}

// wave per destination node: h2[n] = norm[n] * sum_e norm[src_e] * x[src_e]
__global__ __launch_bounds__(256) void aggregate_kernel(
    const float* __restrict__ x, const int* __restrict__ sorted_src,
    const int* __restrict__ row_start, const float* __restrict__ norm,
    float* __restrict__ h2, int N) {
    int wave = (int)((blockIdx.x * blockDim.x + threadIdx.x) >> 6);
    int lane = threadIdx.x & 63;
    if (wave >= N) return;
    int s = row_start[wave];
    int t = row_start[wave + 1];
    float2 acc = {0.0f, 0.0f};
    for (int base = s; base < t; base += 64) {
        int cnt = min(64, t - base);
        int my = 0;
        float mynrm = 0.0f;
        if (lane < cnt) {
            my = sorted_src[base + lane];
            mynrm = norm[my];
        }
        int j = 0;
        for (; j + 7 < cnt; j += 8) {  // 8 outstanding row loads to hide L2/L3 latency
            int i0 = __shfl(my, j + 0, 64), i1 = __shfl(my, j + 1, 64);
            int i2 = __shfl(my, j + 2, 64), i3 = __shfl(my, j + 3, 64);
            int i4 = __shfl(my, j + 4, 64), i5 = __shfl(my, j + 5, 64);
            int i6 = __shfl(my, j + 6, 64), i7 = __shfl(my, j + 7, 64);
            float n0 = __shfl(mynrm, j + 0, 64), n1 = __shfl(mynrm, j + 1, 64);
            float n2 = __shfl(mynrm, j + 2, 64), n3 = __shfl(mynrm, j + 3, 64);
            float n4 = __shfl(mynrm, j + 4, 64), n5 = __shfl(mynrm, j + 5, 64);
            float n6 = __shfl(mynrm, j + 6, 64), n7 = __shfl(mynrm, j + 7, 64);
            float2 v0 = *(const float2*)(x + (size_t)i0 * D + 2 * lane);
            float2 v1 = *(const float2*)(x + (size_t)i1 * D + 2 * lane);
            float2 v2 = *(const float2*)(x + (size_t)i2 * D + 2 * lane);
            float2 v3 = *(const float2*)(x + (size_t)i3 * D + 2 * lane);
            float2 v4 = *(const float2*)(x + (size_t)i4 * D + 2 * lane);
            float2 v5 = *(const float2*)(x + (size_t)i5 * D + 2 * lane);
            float2 v6 = *(const float2*)(x + (size_t)i6 * D + 2 * lane);
            float2 v7 = *(const float2*)(x + (size_t)i7 * D + 2 * lane);
            acc.x = fmaf(n0, v0.x, acc.x); acc.y = fmaf(n0, v0.y, acc.y);
            acc.x = fmaf(n1, v1.x, acc.x); acc.y = fmaf(n1, v1.y, acc.y);
            acc.x = fmaf(n2, v2.x, acc.x); acc.y = fmaf(n2, v2.y, acc.y);
            acc.x = fmaf(n3, v3.x, acc.x); acc.y = fmaf(n3, v3.y, acc.y);
            acc.x = fmaf(n4, v4.x, acc.x); acc.y = fmaf(n4, v4.y, acc.y);
            acc.x = fmaf(n5, v5.x, acc.x); acc.y = fmaf(n5, v5.y, acc.y);
            acc.x = fmaf(n6, v6.x, acc.x); acc.y = fmaf(n6, v6.y, acc.y);
            acc.x = fmaf(n7, v7.x, acc.x); acc.y = fmaf(n7, v7.y, acc.y);
        }
        for (; j < cnt; ++j) {
            int i0 = __shfl(my, j, 64);
            float n0 = __shfl(mynrm, j, 64);
            float2 v0 = *(const float2*)(x + (size_t)i0 * D + 2 * lane);
            acc.x = fmaf(n0, v0.x, acc.x);
            acc.y = fmaf(n0, v0.y, acc.y);
        }
    }
    float nrm = norm[wave];
    float2 o = {acc.x * nrm, acc.y * nrm};
    *(float2*)(h2 + (size_t)wave * D + 2 * lane) = o;
}

// fused: out = relu(relu(h2 @ Wc^T + bc) @ Wl^T + bl)
// 64 rows/block, 512 threads. rg = tid&15 (low bits), cg = tid>>4 (high bits):
//  - W reads: all 16 lanes of a group share the address -> broadcast, from GLOBAL (L2)
//  - ht in LDS, XOR-swizzled 16B slots: slot = (k>>2) ^ ((row>>2)&7) -> conflict-free
#define MLP_ROWS 64

__device__ __forceinline__ float dot4(float4 h, float4 w, float acc) {
    acc = fmaf(h.x, w.x, acc);
    acc = fmaf(h.y, w.y, acc);
    acc = fmaf(h.z, w.z, acc);
    acc = fmaf(h.w, w.w, acc);
    return acc;
}

__global__ __launch_bounds__(512, 2) void mlp_kernel(
    const float* __restrict__ h2, const float* __restrict__ wc, const float* __restrict__ bc,
    const float* __restrict__ wl, const float* __restrict__ bl,
    float* __restrict__ out, int N) {
    __shared__ float ht[MLP_ROWS * 128];  // XOR-swizzled 16B slots
    int tid = threadIdx.x;
    int row0 = blockIdx.x * MLP_ROWS;
    int rg = tid & 15, cg = tid >> 4;     // 16 row-groups x 32 col-groups
    int r0 = rg << 2, o0 = cg << 2;
    int key = rg & 7;

    // stage h2 tile (swizzled write; lanes within 8-lane phase hit distinct banks)
    for (int i = 0; i < 4; ++i) {
        int flat = (tid << 2) + (i << 11);
        int r = flat >> 7, k = flat & 127;
        int grow = row0 + r;
        float4 v = make_float4(0.f, 0.f, 0.f, 0.f);
        if (grow < N) v = *(const float4*)(h2 + (size_t)grow * D + k);
        *(float4*)(ht + r * 128 + ((((k >> 2) ^ ((r >> 2) & 7))) << 2)) = v;
    }
    __syncthreads();

    float acc[4][4];  // [row][col]

    // ---- layer 1 ----
    {
        float4 b4 = *(const float4*)(bc + o0);
        for (int i = 0; i < 4; ++i) { acc[i][0] = b4.x; acc[i][1] = b4.y; acc[i][2] = b4.z; acc[i][3] = b4.w; }
        #pragma unroll 4
        for (int k = 0; k < 128; k += 4) {
            float4 w0 = *(const float4*)(wc + (size_t)(o0 + 0) * D + k);
            float4 w1 = *(const float4*)(wc + (size_t)(o0 + 1) * D + k);
            float4 w2 = *(const float4*)(wc + (size_t)(o0 + 2) * D + k);
            float4 w3 = *(const float4*)(wc + (size_t)(o0 + 3) * D + k);
            int so = (((k >> 2) ^ key) << 2);
            float4 h0 = *(const float4*)(ht + (r0 + 0) * 128 + so);
            float4 h1 = *(const float4*)(ht + (r0 + 1) * 128 + so);
            float4 h2v = *(const float4*)(ht + (r0 + 2) * 128 + so);
            float4 h3v = *(const float4*)(ht + (r0 + 3) * 128 + so);
            acc[0][0] = dot4(h0, w0, acc[0][0]); acc[0][1] = dot4(h0, w1, acc[0][1]);
            acc[0][2] = dot4(h0, w2, acc[0][2]); acc[0][3] = dot4(h0, w3, acc[0][3]);
            acc[1][0] = dot4(h1, w0, acc[1][0]); acc[1][1] = dot4(h1, w1, acc[1][1]);
            acc[1][2] = dot4(h1, w2, acc[1][2]); acc[1][3] = dot4(h1, w3, acc[1][3]);
            acc[2][0] = dot4(h2v, w0, acc[2][0]); acc[2][1] = dot4(h2v, w1, acc[2][1]);
            acc[2][2] = dot4(h2v, w2, acc[2][2]); acc[2][3] = dot4(h2v, w3, acc[2][3]);
            acc[3][0] = dot4(h3v, w0, acc[3][0]); acc[3][1] = dot4(h3v, w1, acc[3][1]);
            acc[3][2] = dot4(h3v, w2, acc[3][2]); acc[3][3] = dot4(h3v, w3, acc[3][3]);
        }
    }
    __syncthreads();  // all layer-1 reads of ht done before overwrite

    // write h3 = relu(acc) into ht (swizzled); slot for k=o0 is cg^key
    for (int r = 0; r < 4; ++r) {
        float4 v = make_float4(fmaxf(acc[r][0], 0.f), fmaxf(acc[r][1], 0.f),
                               fmaxf(acc[r][2], 0.f), fmaxf(acc[r][3], 0.f));
        *(float4*)(ht + (r0 + r) * 128 + ((cg ^ key) << 2)) = v;
    }
    __syncthreads();

    // ---- layer 2 ----
    {
        float4 b4 = *(const float4*)(bl + o0);
        for (int i = 0; i < 4; ++i) { acc[i][0] = b4.x; acc[i][1] = b4.y; acc[i][2] = b4.z; acc[i][3] = b4.w; }
        #pragma unroll 4
        for (int k = 0; k < 128; k += 4) {
            float4 w0 = *(const float4*)(wl + (size_t)(o0 + 0) * D + k);
            float4 w1 = *(const float4*)(wl + (size_t)(o0 + 1) * D + k);
            float4 w2 = *(const float4*)(wl + (size_t)(o0 + 2) * D + k);
            float4 w3 = *(const float4*)(wl + (size_t)(o0 + 3) * D + k);
            int so = (((k >> 2) ^ key) << 2);
            float4 h0 = *(const float4*)(ht + (r0 + 0) * 128 + so);
            float4 h1 = *(const float4*)(ht + (r0 + 1) * 128 + so);
            float4 h2v = *(const float4*)(ht + (r0 + 2) * 128 + so);
            float4 h3v = *(const float4*)(ht + (r0 + 3) * 128 + so);
            acc[0][0] = dot4(h0, w0, acc[0][0]); acc[0][1] = dot4(h0, w1, acc[0][1]);
            acc[0][2] = dot4(h0, w2, acc[0][2]); acc[0][3] = dot4(h0, w3, acc[0][3]);
            acc[1][0] = dot4(h1, w0, acc[1][0]); acc[1][1] = dot4(h1, w1, acc[1][1]);
            acc[1][2] = dot4(h1, w2, acc[1][2]); acc[1][3] = dot4(h1, w3, acc[1][3]);
            acc[2][0] = dot4(h2v, w0, acc[2][0]); acc[2][1] = dot4(h2v, w1, acc[2][1]);
            acc[2][2] = dot4(h2v, w2, acc[2][2]); acc[2][3] = dot4(h2v, w3, acc[2][3]);
            acc[3][0] = dot4(h3v, w0, acc[3][0]); acc[3][1] = dot4(h3v, w1, acc[3][1]);
            acc[3][2] = dot4(h3v, w2, acc[3][2]); acc[3][3] = dot4(h3v, w3, acc[3][3]);
        }
    }
    __syncthreads();  // all layer-2 reads of ht done before overwrite

    // write h4 = relu(acc) into ht (swizzled), then coalesced copy-out
    for (int r = 0; r < 4; ++r) {
        float4 v = make_float4(fmaxf(acc[r][0], 0.f), fmaxf(acc[r][1], 0.f),
                               fmaxf(acc[r][2], 0.f), fmaxf(acc[r][3], 0.f));
        *(float4*)(ht + (r0 + r) * 128 + ((cg ^ key) << 2)) = v;
    }
    __syncthreads();

    for (int i = 0; i < 4; ++i) {
        int flat = (tid << 2) + (i << 11);
        int r = flat >> 7, k = flat & 127;
        int grow = row0 + r;
        float4 v = *(const float4*)(ht + r * 128 + ((((k >> 2) ^ ((r >> 2) & 7))) << 2));
        if (grow < N) *(float4*)(out + (size_t)grow * D + k) = v;
    }
}

extern "C" void kernel_launch(void* const* d_in, const int* in_sizes, int n_in,
                              void* d_out, int out_size, void* d_ws, size_t ws_size,
                              hipStream_t stream) {
    const float* x      = (const float*)d_in[0];
    const int*   src    = (const int*)d_in[1];
    const int*   dst    = (const int*)d_in[2];
    const float* wc     = (const float*)d_in[3];
    const float* bc     = (const float*)d_in[4];
    const float* wl     = (const float*)d_in[5];
    const float* bl     = (const float*)d_in[6];
    float* out = (float*)d_out;

    int N = in_sizes[0] / D;
    int E = in_sizes[1];

    // workspace carve-up (256B aligned)
    size_t off = 0;
    auto carve = [&](size_t bytes) -> void* {
        void* p = (char*)d_ws + off;
        off += (bytes + 255) & ~(size_t)255;
        return p;
    };
    float* h2        = (float*)carve((size_t)N * D * 4);
    int*   deg       = (int*)carve((size_t)N * 4);
    int*   row_start = (int*)carve((size_t)(N + 1) * 4);
    int*   cursor    = (int*)carve((size_t)N * 4);
    float* norm      = (float*)carve((size_t)N * 4);
    int*   blockSums = (int*)carve(1024 * 4);
    int*   sorted    = (int*)carve((size_t)E * 4);
    (void)ws_size;

    hipMemsetAsync(deg, 0, (size_t)N * 4, stream);

    int nScanBlocks = (N + SCAN_TILE - 1) / SCAN_TILE;

    degree_kernel<<<(E / 4 + 255) / 256, 256, 0, stream>>>(dst, deg, E);
    scan_partial_kernel<<<nScanBlocks, 256, 0, stream>>>(deg, blockSums, N);
    scan_blocksums_kernel<<<1, 256, 0, stream>>>(blockSums, nScanBlocks);
    scan_final_kernel<<<nScanBlocks, 256, 0, stream>>>(deg, blockSums, row_start, cursor, norm, N, E);
    binning_kernel<<<(E / 4 + 255) / 256, 256, 0, stream>>>(src, dst, cursor, sorted, E);
    aggregate_kernel<<<(N + 3) / 4, 256, 0, stream>>>(x, sorted, row_start, norm, h2, N);
    mlp_kernel<<<(N + MLP_ROWS - 1) / MLP_ROWS, 512, 0, stream>>>(h2, wc, bc, wl, bl, out, N);
}

// Round 5
// 300.905 us; speedup vs baseline: 1.5256x; 1.0011x over previous
//
#include <hip/hip_runtime.h>

// SGConv (k=1) + Linear, fused pipeline:
//   1) deg[dst]++                   (histogram, int atomics, int4 edge reads)
//   2) exclusive scan(deg)          (3-phase multi-block scan; emits norm[])
//   3) counting-sort edges by dst   (atomic binning, int4 edge reads)
//   4) xs = x * norm                (stream pass)
//   5) h2[n] = norm[n] * sum_e xs[src_e]   (wave per node, no atomics, 8-deep gather)
//   6) out = relu(relu(h2 @ Wc^T + bc) @ Wl^T + bl)   (fused double GEMM, fp32 VALU)
//      - 256 thr / 32-row tiles: high occupancy; W broadcast from global (L2)
//      - ht in LDS, XOR-swizzled 16B slots (conflict-free all phases)

#define D 128
#define SCAN_TILE 1024  // 256 threads * 4 elements

__global__ void degree_kernel(const int* __restrict__ dst, int* __restrict__ deg, int E) {
    int i = (blockIdx.x * blockDim.x + threadIdx.x) << 2;
    if (i + 3 < E) {
        int4 d = *(const int4*)(dst + i);
        atomicAdd(&deg[d.x], 1);
        atomicAdd(&deg[d.y], 1);
        atomicAdd(&deg[d.z], 1);
        atomicAdd(&deg[d.w], 1);
    } else {
        for (int j = i; j < E; ++j) atomicAdd(&deg[dst[j]], 1);
    }
}

// ---- 3-phase exclusive scan over deg[0..N) -> row_start[0..N], cursor, norm ----
__global__ __launch_bounds__(256) void scan_partial_kernel(const int* __restrict__ deg,
                                                           int* __restrict__ blockSums, int N) {
    int tid = threadIdx.x;
    int base = blockIdx.x * SCAN_TILE + (tid << 2);
    int4 v = make_int4(0, 0, 0, 0);
    if (base + 3 < N) v = *(const int4*)(deg + base);
    else {
        if (base + 0 < N) v.x = deg[base + 0];
        if (base + 1 < N) v.y = deg[base + 1];
        if (base + 2 < N) v.z = deg[base + 2];
        if (base + 3 < N) v.w = deg[base + 3];
    }
    int s = v.x + v.y + v.z + v.w;
    for (int off = 32; off; off >>= 1) s += __shfl_down(s, off, 64);
    __shared__ int ws[4];
    if ((tid & 63) == 0) ws[tid >> 6] = s;
    __syncthreads();
    if (tid == 0) blockSums[blockIdx.x] = ws[0] + ws[1] + ws[2] + ws[3];
}

__global__ __launch_bounds__(256) void scan_blocksums_kernel(int* __restrict__ blockSums, int B) {
    __shared__ int s[256];
    int tid = threadIdx.x;
    int v = (tid < B) ? blockSums[tid] : 0;
    s[tid] = v;
    __syncthreads();
    for (int off = 1; off < 256; off <<= 1) {
        int u = (tid >= off) ? s[tid - off] : 0;
        __syncthreads();
        s[tid] += u;
        __syncthreads();
    }
    if (tid < B) blockSums[tid] = (tid == 0) ? 0 : s[tid - 1];
}

__global__ __launch_bounds__(256) void scan_final_kernel(
    const int* __restrict__ deg, const int* __restrict__ blockSums,
    int* __restrict__ row_start, int* __restrict__ cursor,
    float* __restrict__ norm, int N, int E) {
    int tid = threadIdx.x;
    int base = blockIdx.x * SCAN_TILE + (tid << 2);
    int4 v = make_int4(0, 0, 0, 0);
    if (base + 3 < N) v = *(const int4*)(deg + base);
    else {
        if (base + 0 < N) v.x = deg[base + 0];
        if (base + 1 < N) v.y = deg[base + 1];
        if (base + 2 < N) v.z = deg[base + 2];
        if (base + 3 < N) v.w = deg[base + 3];
    }
    int local = v.x + v.y + v.z + v.w;
    int lane = tid & 63, w = tid >> 6;
    int inc = local;
    for (int off = 1; off < 64; off <<= 1) {
        int u = __shfl_up(inc, off, 64);
        if (lane >= off) inc += u;
    }
    __shared__ int wsum[4];
    if (lane == 63) wsum[w] = inc;
    __syncthreads();
    int woff = 0;
    for (int i = 0; i < w; ++i) woff += wsum[i];
    int ex = (inc - local) + woff + blockSums[blockIdx.x];
    int4 rs;
    rs.x = ex;
    rs.y = rs.x + v.x;
    rs.z = rs.y + v.y;
    rs.w = rs.z + v.z;
    float4 nm;
    nm.x = rsqrtf(fmaxf((float)v.x, 1.0f));
    nm.y = rsqrtf(fmaxf((float)v.y, 1.0f));
    nm.z = rsqrtf(fmaxf((float)v.z, 1.0f));
    nm.w = rsqrtf(fmaxf((float)v.w, 1.0f));
    if (base + 3 < N) {
        *(int4*)(row_start + base) = rs;
        *(int4*)(cursor + base) = rs;
        *(float4*)(norm + base) = nm;
    } else {
        if (base + 0 < N) { row_start[base + 0] = rs.x; cursor[base + 0] = rs.x; norm[base + 0] = nm.x; }
        if (base + 1 < N) { row_start[base + 1] = rs.y; cursor[base + 1] = rs.y; norm[base + 1] = nm.y; }
        if (base + 2 < N) { row_start[base + 2] = rs.z; cursor[base + 2] = rs.z; norm[base + 2] = nm.z; }
    }
    if (blockIdx.x == 0 && tid == 0) row_start[N] = E;
}

__global__ void binning_kernel(const int* __restrict__ src, const int* __restrict__ dst,
                               int* __restrict__ cursor, int* __restrict__ sorted_src, int E) {
    int i = (blockIdx.x * blockDim.x + threadIdx.x) << 2;
    if (i + 3 < E) {
        int4 d = *(const int4*)(dst + i);
        int4 s = *(const int4*)(src + i);
        sorted_src[atomicAdd(&cursor[d.x], 1)] = s.x;
        sorted_src[atomicAdd(&cursor[d.y], 1)] = s.y;
        sorted_src[atomicAdd(&cursor[d.z], 1)] = s.z;
        sorted_src[atomicAdd(&cursor[d.w], 1)] = s.w;
    } else {
        for (int j = i; j < E; ++j) {
            int p = atomicAdd(&cursor[dst[j]], 1);
            sorted_src[p] = src[j];
        }
    }
}

// xs = x * norm[row]  (float4 over N*32)
__global__ void scale_kernel(const float* __restrict__ x, const float* __restrict__ norm,
                             float* __restrict__ xs, int N) {
    int idx = blockIdx.x * blockDim.x + threadIdx.x;
    int total = N * (D / 4);
    if (idx >= total) return;
    int row = idx >> 5;  // D/4 == 32
    float nrm = norm[row];
    float4 v = ((const float4*)x)[idx];
    v.x *= nrm; v.y *= nrm; v.z *= nrm; v.w *= nrm;
    ((float4*)xs)[idx] = v;
}

// wave per destination node: h2[n] = norm[n] * sum over its edges of xs[src]
__global__ __launch_bounds__(256) void aggregate_kernel(
    const float* __restrict__ xs, const int* __restrict__ sorted_src,
    const int* __restrict__ row_start, const float* __restrict__ norm,
    float* __restrict__ h2, int N) {
    int wave = (int)((blockIdx.x * blockDim.x + threadIdx.x) >> 6);
    int lane = threadIdx.x & 63;
    if (wave >= N) return;
    int s = row_start[wave];
    int t = row_start[wave + 1];
    float2 acc = {0.0f, 0.0f};
    for (int base = s; base < t; base += 64) {
        int cnt = min(64, t - base);
        int my = (lane < cnt) ? sorted_src[base + lane] : 0;
        int j = 0;
        for (; j + 7 < cnt; j += 8) {  // 8 outstanding row loads to hide L2/L3 latency
            int i0 = __shfl(my, j + 0, 64), i1 = __shfl(my, j + 1, 64);
            int i2 = __shfl(my, j + 2, 64), i3 = __shfl(my, j + 3, 64);
            int i4 = __shfl(my, j + 4, 64), i5 = __shfl(my, j + 5, 64);
            int i6 = __shfl(my, j + 6, 64), i7 = __shfl(my, j + 7, 64);
            float2 v0 = *(const float2*)(xs + (size_t)i0 * D + 2 * lane);
            float2 v1 = *(const float2*)(xs + (size_t)i1 * D + 2 * lane);
            float2 v2 = *(const float2*)(xs + (size_t)i2 * D + 2 * lane);
            float2 v3 = *(const float2*)(xs + (size_t)i3 * D + 2 * lane);
            float2 v4 = *(const float2*)(xs + (size_t)i4 * D + 2 * lane);
            float2 v5 = *(const float2*)(xs + (size_t)i5 * D + 2 * lane);
            float2 v6 = *(const float2*)(xs + (size_t)i6 * D + 2 * lane);
            float2 v7 = *(const float2*)(xs + (size_t)i7 * D + 2 * lane);
            acc.x += (v0.x + v1.x) + (v2.x + v3.x) + (v4.x + v5.x) + (v6.x + v7.x);
            acc.y += (v0.y + v1.y) + (v2.y + v3.y) + (v4.y + v5.y) + (v6.y + v7.y);
        }
        for (; j < cnt; ++j) {
            int i0 = __shfl(my, j, 64);
            float2 v0 = *(const float2*)(xs + (size_t)i0 * D + 2 * lane);
            acc.x += v0.x;
            acc.y += v0.y;
        }
    }
    float nrm = norm[wave];
    float2 o = {acc.x * nrm, acc.y * nrm};
    *(float2*)(h2 + (size_t)wave * D + 2 * lane) = o;
}

// fused: out = relu(relu(h2 @ Wc^T + bc) @ Wl^T + bl)
// 32 rows/block, 256 threads. rg = tid&7, cg = tid>>3:
//  - W reads: 8 lanes of a cg-group share the address -> broadcast, from GLOBAL (L2)
//  - ht in LDS, XOR-swizzled 16B slots: slot = (k>>2) ^ rg -> conflict-free
#define MLP_ROWS 32

__device__ __forceinline__ float dot4(float4 h, float4 w, float acc) {
    acc = fmaf(h.x, w.x, acc);
    acc = fmaf(h.y, w.y, acc);
    acc = fmaf(h.z, w.z, acc);
    acc = fmaf(h.w, w.w, acc);
    return acc;
}

__global__ __launch_bounds__(256, 4) void mlp_kernel(
    const float* __restrict__ h2, const float* __restrict__ wc, const float* __restrict__ bc,
    const float* __restrict__ wl, const float* __restrict__ bl,
    float* __restrict__ out, int N) {
    __shared__ float ht[MLP_ROWS * 128];  // 16 KB, XOR-swizzled 16B slots
    int tid = threadIdx.x;
    int row0 = blockIdx.x * MLP_ROWS;
    int rg = tid & 7, cg = tid >> 3;      // 8 row-groups x 32 col-groups
    int r0 = rg << 2, o0 = cg << 2;
    int key = rg;                          // 0..7

    // stage h2 tile (swizzled write; within a row, 32 lanes hit distinct slots)
    for (int i = 0; i < 4; ++i) {
        int flat = (tid << 2) + (i << 10);
        int r = flat >> 7, k = flat & 127;
        int grow = row0 + r;
        float4 v = make_float4(0.f, 0.f, 0.f, 0.f);
        if (grow < N) v = *(const float4*)(h2 + (size_t)grow * D + k);
        *(float4*)(ht + r * 128 + ((((k >> 2) ^ ((r >> 2) & 7))) << 2)) = v;
    }
    __syncthreads();

    float acc[4][4];  // [row][col]

    // ---- layer 1 ----
    {
        float4 b4 = *(const float4*)(bc + o0);
        for (int i = 0; i < 4; ++i) { acc[i][0] = b4.x; acc[i][1] = b4.y; acc[i][2] = b4.z; acc[i][3] = b4.w; }
        #pragma unroll 8
        for (int k = 0; k < 128; k += 4) {
            float4 w0 = *(const float4*)(wc + (size_t)(o0 + 0) * D + k);
            float4 w1 = *(const float4*)(wc + (size_t)(o0 + 1) * D + k);
            float4 w2 = *(const float4*)(wc + (size_t)(o0 + 2) * D + k);
            float4 w3 = *(const float4*)(wc + (size_t)(o0 + 3) * D + k);
            int so = (((k >> 2) ^ key) << 2);
            float4 h0 = *(const float4*)(ht + (r0 + 0) * 128 + so);
            float4 h1 = *(const float4*)(ht + (r0 + 1) * 128 + so);
            float4 h2v = *(const float4*)(ht + (r0 + 2) * 128 + so);
            float4 h3v = *(const float4*)(ht + (r0 + 3) * 128 + so);
            acc[0][0] = dot4(h0, w0, acc[0][0]); acc[0][1] = dot4(h0, w1, acc[0][1]);
            acc[0][2] = dot4(h0, w2, acc[0][2]); acc[0][3] = dot4(h0, w3, acc[0][3]);
            acc[1][0] = dot4(h1, w0, acc[1][0]); acc[1][1] = dot4(h1, w1, acc[1][1]);
            acc[1][2] = dot4(h1, w2, acc[1][2]); acc[1][3] = dot4(h1, w3, acc[1][3]);
            acc[2][0] = dot4(h2v, w0, acc[2][0]); acc[2][1] = dot4(h2v, w1, acc[2][1]);
            acc[2][2] = dot4(h2v, w2, acc[2][2]); acc[2][3] = dot4(h2v, w3, acc[2][3]);
            acc[3][0] = dot4(h3v, w0, acc[3][0]); acc[3][1] = dot4(h3v, w1, acc[3][1]);
            acc[3][2] = dot4(h3v, w2, acc[3][2]); acc[3][3] = dot4(h3v, w3, acc[3][3]);
        }
    }
    __syncthreads();  // all layer-1 reads of ht done before overwrite

    // write h3 = relu(acc) into ht (swizzled); slot for k=o0 is cg^key
    for (int r = 0; r < 4; ++r) {
        float4 v = make_float4(fmaxf(acc[r][0], 0.f), fmaxf(acc[r][1], 0.f),
                               fmaxf(acc[r][2], 0.f), fmaxf(acc[r][3], 0.f));
        *(float4*)(ht + (r0 + r) * 128 + ((cg ^ key) << 2)) = v;
    }
    __syncthreads();

    // ---- layer 2 ----
    {
        float4 b4 = *(const float4*)(bl + o0);
        for (int i = 0; i < 4; ++i) { acc[i][0] = b4.x; acc[i][1] = b4.y; acc[i][2] = b4.z; acc[i][3] = b4.w; }
        #pragma unroll 8
        for (int k = 0; k < 128; k += 4) {
            float4 w0 = *(const float4*)(wl + (size_t)(o0 + 0) * D + k);
            float4 w1 = *(const float4*)(wl + (size_t)(o0 + 1) * D + k);
            float4 w2 = *(const float4*)(wl + (size_t)(o0 + 2) * D + k);
            float4 w3 = *(const float4*)(wl + (size_t)(o0 + 3) * D + k);
            int so = (((k >> 2) ^ key) << 2);
            float4 h0 = *(const float4*)(ht + (r0 + 0) * 128 + so);
            float4 h1 = *(const float4*)(ht + (r0 + 1) * 128 + so);
            float4 h2v = *(const float4*)(ht + (r0 + 2) * 128 + so);
            float4 h3v = *(const float4*)(ht + (r0 + 3) * 128 + so);
            acc[0][0] = dot4(h0, w0, acc[0][0]); acc[0][1] = dot4(h0, w1, acc[0][1]);
            acc[0][2] = dot4(h0, w2, acc[0][2]); acc[0][3] = dot4(h0, w3, acc[0][3]);
            acc[1][0] = dot4(h1, w0, acc[1][0]); acc[1][1] = dot4(h1, w1, acc[1][1]);
            acc[1][2] = dot4(h1, w2, acc[1][2]); acc[1][3] = dot4(h1, w3, acc[1][3]);
            acc[2][0] = dot4(h2v, w0, acc[2][0]); acc[2][1] = dot4(h2v, w1, acc[2][1]);
            acc[2][2] = dot4(h2v, w2, acc[2][2]); acc[2][3] = dot4(h2v, w3, acc[2][3]);
            acc[3][0] = dot4(h3v, w0, acc[3][0]); acc[3][1] = dot4(h3v, w1, acc[3][1]);
            acc[3][2] = dot4(h3v, w2, acc[3][2]); acc[3][3] = dot4(h3v, w3, acc[3][3]);
        }
    }
    __syncthreads();  // all layer-2 reads of ht done before overwrite

    // write h4 = relu(acc) into ht (swizzled), then coalesced copy-out
    for (int r = 0; r < 4; ++r) {
        float4 v = make_float4(fmaxf(acc[r][0], 0.f), fmaxf(acc[r][1], 0.f),
                               fmaxf(acc[r][2], 0.f), fmaxf(acc[r][3], 0.f));
        *(float4*)(ht + (r0 + r) * 128 + ((cg ^ key) << 2)) = v;
    }
    __syncthreads();

    for (int i = 0; i < 4; ++i) {
        int flat = (tid << 2) + (i << 10);
        int r = flat >> 7, k = flat & 127;
        int grow = row0 + r;
        float4 v = *(const float4*)(ht + r * 128 + ((((k >> 2) ^ ((r >> 2) & 7))) << 2));
        if (grow < N) *(float4*)(out + (size_t)grow * D + k) = v;
    }
}

extern "C" void kernel_launch(void* const* d_in, const int* in_sizes, int n_in,
                              void* d_out, int out_size, void* d_ws, size_t ws_size,
                              hipStream_t stream) {
    const float* x      = (const float*)d_in[0];
    const int*   src    = (const int*)d_in[1];
    const int*   dst    = (const int*)d_in[2];
    const float* wc     = (const float*)d_in[3];
    const float* bc     = (const float*)d_in[4];
    const float* wl     = (const float*)d_in[5];
    const float* bl     = (const float*)d_in[6];
    float* out = (float*)d_out;

    int N = in_sizes[0] / D;
    int E = in_sizes[1];

    // workspace carve-up (256B aligned)
    size_t off = 0;
    auto carve = [&](size_t bytes) -> void* {
        void* p = (char*)d_ws + off;
        off += (bytes + 255) & ~(size_t)255;
        return p;
    };
    float* xs        = (float*)carve((size_t)N * D * 4);
    float* h2        = (float*)carve((size_t)N * D * 4);
    int*   deg       = (int*)carve((size_t)N * 4);
    int*   row_start = (int*)carve((size_t)(N + 1) * 4);
    int*   cursor    = (int*)carve((size_t)N * 4);
    float* norm      = (float*)carve((size_t)N * 4);
    int*   blockSums = (int*)carve(1024 * 4);
    int*   sorted    = (int*)carve((size_t)E * 4);
    (void)ws_size;

    hipMemsetAsync(deg, 0, (size_t)N * 4, stream);

    int nScanBlocks = (N + SCAN_TILE - 1) / SCAN_TILE;

    degree_kernel<<<(E / 4 + 255) / 256, 256, 0, stream>>>(dst, deg, E);
    scan_partial_kernel<<<nScanBlocks, 256, 0, stream>>>(deg, blockSums, N);
    scan_blocksums_kernel<<<1, 256, 0, stream>>>(blockSums, nScanBlocks);
    scan_final_kernel<<<nScanBlocks, 256, 0, stream>>>(deg, blockSums, row_start, cursor, norm, N, E);
    binning_kernel<<<(E / 4 + 255) / 256, 256, 0, stream>>>(src, dst, cursor, sorted, E);
    {
        int total = N * (D / 4);
        scale_kernel<<<(total + 255) / 256, 256, 0, stream>>>(x, norm, xs, N);
    }
    aggregate_kernel<<<(N + 3) / 4, 256, 0, stream>>>(xs, sorted, row_start, norm, h2, N);
    mlp_kernel<<<(N + MLP_ROWS - 1) / MLP_ROWS, 256, 0, stream>>>(h2, wc, bc, wl, bl, out, N);
}

// Round 6
// 294.934 us; speedup vs baseline: 1.5565x; 1.0202x over previous
//
#include <hip/hip_runtime.h>

// SGConv (k=1) + Linear, fused pipeline:
//   1) deg[dst]++                   (histogram, int atomics, int4 edge reads)
//   2) exclusive scan(deg)          (3-phase multi-block scan; emits norm[])
//   3) counting-sort edges by dst   (atomic binning, int4 edge reads)
//   4) xs = x * norm                (stream pass)
//   5) h2[n] = norm[n] * sum_e xs[src_e]   (wave per node, no atomics, 8-deep gather)
//   6) out = relu(relu(h2 @ Wc^T + bc) @ Wl^T + bl)
//      NEW: MFMA path. fp32 emulated via 3-way bf16 split (s1+s2+s3), 6 products
//      (i+j<=4) -> ~2^-24 relative error, fp32-grade. Weights pre-split once into
//      6 bf16 arrays (L2-resident, B-frags loaded from global). h tile in LDS f32
//      with 16B-slot XOR swizzle (conflict-free stage/read/transition/copyout).

#define D 128
#define SCAN_TILE 1024  // 256 threads * 4 elements

typedef __attribute__((ext_vector_type(8))) short short8;
typedef __attribute__((ext_vector_type(4))) float f32x4;

__global__ void degree_kernel(const int* __restrict__ dst, int* __restrict__ deg, int E) {
    int i = (blockIdx.x * blockDim.x + threadIdx.x) << 2;
    if (i + 3 < E) {
        int4 d = *(const int4*)(dst + i);
        atomicAdd(&deg[d.x], 1);
        atomicAdd(&deg[d.y], 1);
        atomicAdd(&deg[d.z], 1);
        atomicAdd(&deg[d.w], 1);
    } else {
        for (int j = i; j < E; ++j) atomicAdd(&deg[dst[j]], 1);
    }
}

// ---- 3-phase exclusive scan over deg[0..N) -> row_start[0..N], cursor, norm ----
__global__ __launch_bounds__(256) void scan_partial_kernel(const int* __restrict__ deg,
                                                           int* __restrict__ blockSums, int N) {
    int tid = threadIdx.x;
    int base = blockIdx.x * SCAN_TILE + (tid << 2);
    int4 v = make_int4(0, 0, 0, 0);
    if (base + 3 < N) v = *(const int4*)(deg + base);
    else {
        if (base + 0 < N) v.x = deg[base + 0];
        if (base + 1 < N) v.y = deg[base + 1];
        if (base + 2 < N) v.z = deg[base + 2];
        if (base + 3 < N) v.w = deg[base + 3];
    }
    int s = v.x + v.y + v.z + v.w;
    for (int off = 32; off; off >>= 1) s += __shfl_down(s, off, 64);
    __shared__ int ws[4];
    if ((tid & 63) == 0) ws[tid >> 6] = s;
    __syncthreads();
    if (tid == 0) blockSums[blockIdx.x] = ws[0] + ws[1] + ws[2] + ws[3];
}

__global__ __launch_bounds__(256) void scan_blocksums_kernel(int* __restrict__ blockSums, int B) {
    __shared__ int s[256];
    int tid = threadIdx.x;
    int v = (tid < B) ? blockSums[tid] : 0;
    s[tid] = v;
    __syncthreads();
    for (int off = 1; off < 256; off <<= 1) {
        int u = (tid >= off) ? s[tid - off] : 0;
        __syncthreads();
        s[tid] += u;
        __syncthreads();
    }
    if (tid < B) blockSums[tid] = (tid == 0) ? 0 : s[tid - 1];
}

__global__ __launch_bounds__(256) void scan_final_kernel(
    const int* __restrict__ deg, const int* __restrict__ blockSums,
    int* __restrict__ row_start, int* __restrict__ cursor,
    float* __restrict__ norm, int N, int E) {
    int tid = threadIdx.x;
    int base = blockIdx.x * SCAN_TILE + (tid << 2);
    int4 v = make_int4(0, 0, 0, 0);
    if (base + 3 < N) v = *(const int4*)(deg + base);
    else {
        if (base + 0 < N) v.x = deg[base + 0];
        if (base + 1 < N) v.y = deg[base + 1];
        if (base + 2 < N) v.z = deg[base + 2];
        if (base + 3 < N) v.w = deg[base + 3];
    }
    int local = v.x + v.y + v.z + v.w;
    int lane = tid & 63, w = tid >> 6;
    int inc = local;
    for (int off = 1; off < 64; off <<= 1) {
        int u = __shfl_up(inc, off, 64);
        if (lane >= off) inc += u;
    }
    __shared__ int wsum[4];
    if (lane == 63) wsum[w] = inc;
    __syncthreads();
    int woff = 0;
    for (int i = 0; i < w; ++i) woff += wsum[i];
    int ex = (inc - local) + woff + blockSums[blockIdx.x];
    int4 rs;
    rs.x = ex;
    rs.y = rs.x + v.x;
    rs.z = rs.y + v.y;
    rs.w = rs.z + v.z;
    float4 nm;
    nm.x = rsqrtf(fmaxf((float)v.x, 1.0f));
    nm.y = rsqrtf(fmaxf((float)v.y, 1.0f));
    nm.z = rsqrtf(fmaxf((float)v.z, 1.0f));
    nm.w = rsqrtf(fmaxf((float)v.w, 1.0f));
    if (base + 3 < N) {
        *(int4*)(row_start + base) = rs;
        *(int4*)(cursor + base) = rs;
        *(float4*)(norm + base) = nm;
    } else {
        if (base + 0 < N) { row_start[base + 0] = rs.x; cursor[base + 0] = rs.x; norm[base + 0] = nm.x; }
        if (base + 1 < N) { row_start[base + 1] = rs.y; cursor[base + 1] = rs.y; norm[base + 1] = nm.y; }
        if (base + 2 < N) { row_start[base + 2] = rs.z; cursor[base + 2] = rs.z; norm[base + 2] = nm.z; }
    }
    if (blockIdx.x == 0 && tid == 0) row_start[N] = E;
}

__global__ void binning_kernel(const int* __restrict__ src, const int* __restrict__ dst,
                               int* __restrict__ cursor, int* __restrict__ sorted_src, int E) {
    int i = (blockIdx.x * blockDim.x + threadIdx.x) << 2;
    if (i + 3 < E) {
        int4 d = *(const int4*)(dst + i);
        int4 s = *(const int4*)(src + i);
        sorted_src[atomicAdd(&cursor[d.x], 1)] = s.x;
        sorted_src[atomicAdd(&cursor[d.y], 1)] = s.y;
        sorted_src[atomicAdd(&cursor[d.z], 1)] = s.z;
        sorted_src[atomicAdd(&cursor[d.w], 1)] = s.w;
    } else {
        for (int j = i; j < E; ++j) {
            int p = atomicAdd(&cursor[dst[j]], 1);
            sorted_src[p] = src[j];
        }
    }
}

// xs = x * norm[row]  (float4 over N*32)
__global__ void scale_kernel(const float* __restrict__ x, const float* __restrict__ norm,
                             float* __restrict__ xs, int N) {
    int idx = blockIdx.x * blockDim.x + threadIdx.x;
    int total = N * (D / 4);
    if (idx >= total) return;
    int row = idx >> 5;  // D/4 == 32
    float nrm = norm[row];
    float4 v = ((const float4*)x)[idx];
    v.x *= nrm; v.y *= nrm; v.z *= nrm; v.w *= nrm;
    ((float4*)xs)[idx] = v;
}

// wave per destination node: h2[n] = norm[n] * sum over its edges of xs[src]
__global__ __launch_bounds__(256) void aggregate_kernel(
    const float* __restrict__ xs, const int* __restrict__ sorted_src,
    const int* __restrict__ row_start, const float* __restrict__ norm,
    float* __restrict__ h2, int N) {
    int wave = (int)((blockIdx.x * blockDim.x + threadIdx.x) >> 6);
    int lane = threadIdx.x & 63;
    if (wave >= N) return;
    int s = row_start[wave];
    int t = row_start[wave + 1];
    float2 acc = {0.0f, 0.0f};
    for (int base = s; base < t; base += 64) {
        int cnt = min(64, t - base);
        int my = (lane < cnt) ? sorted_src[base + lane] : 0;
        int j = 0;
        for (; j + 7 < cnt; j += 8) {  // 8 outstanding row loads to hide L2/L3 latency
            int i0 = __shfl(my, j + 0, 64), i1 = __shfl(my, j + 1, 64);
            int i2 = __shfl(my, j + 2, 64), i3 = __shfl(my, j + 3, 64);
            int i4 = __shfl(my, j + 4, 64), i5 = __shfl(my, j + 5, 64);
            int i6 = __shfl(my, j + 6, 64), i7 = __shfl(my, j + 7, 64);
            float2 v0 = *(const float2*)(xs + (size_t)i0 * D + 2 * lane);
            float2 v1 = *(const float2*)(xs + (size_t)i1 * D + 2 * lane);
            float2 v2 = *(const float2*)(xs + (size_t)i2 * D + 2 * lane);
            float2 v3 = *(const float2*)(xs + (size_t)i3 * D + 2 * lane);
            float2 v4 = *(const float2*)(xs + (size_t)i4 * D + 2 * lane);
            float2 v5 = *(const float2*)(xs + (size_t)i5 * D + 2 * lane);
            float2 v6 = *(const float2*)(xs + (size_t)i6 * D + 2 * lane);
            float2 v7 = *(const float2*)(xs + (size_t)i7 * D + 2 * lane);
            acc.x += (v0.x + v1.x) + (v2.x + v3.x) + (v4.x + v5.x) + (v6.x + v7.x);
            acc.y += (v0.y + v1.y) + (v2.y + v3.y) + (v4.y + v5.y) + (v6.y + v7.y);
        }
        for (; j < cnt; ++j) {
            int i0 = __shfl(my, j, 64);
            float2 v0 = *(const float2*)(xs + (size_t)i0 * D + 2 * lane);
            acc.x += v0.x;
            acc.y += v0.y;
        }
    }
    float nrm = norm[wave];
    float2 o = {acc.x * nrm, acc.y * nrm};
    *(float2*)(h2 + (size_t)wave * D + 2 * lane) = o;
}

// ---------------- MFMA MLP ----------------
__device__ __forceinline__ unsigned short f2bf(float f) {
    union { float f; unsigned u; } c; c.f = f;
    unsigned u = c.u;
    unsigned r = u + 0x7FFFu + ((u >> 16) & 1u);  // RNE
    return (unsigned short)(r >> 16);
}
__device__ __forceinline__ float bf2f(unsigned short b) {
    union { unsigned u; float f; } c; c.u = ((unsigned)b) << 16;
    return c.f;
}

// weight prep: split each fp32 into 3 bf16 terms (exact fp32 emulation basis)
__global__ __launch_bounds__(256) void prep_w_kernel(
    const float* __restrict__ wc, const float* __restrict__ wl,
    unsigned short* __restrict__ w1c, unsigned short* __restrict__ w2c, unsigned short* __restrict__ w3c,
    unsigned short* __restrict__ w1l, unsigned short* __restrict__ w2l, unsigned short* __restrict__ w3l) {
    int idx = blockIdx.x * 256 + threadIdx.x;
    const float* src = (idx < 16384) ? wc : wl;
    int j = idx & 16383;
    float x = src[j];
    unsigned short c1 = f2bf(x);
    float r = x - bf2f(c1);
    unsigned short c2 = f2bf(r);
    float r2 = r - bf2f(c2);
    unsigned short c3 = f2bf(r2);
    if (idx < 16384) { w1c[j] = c1; w2c[j] = c2; w3c[j] = c3; }
    else             { w1l[j] = c1; w2l[j] = c2; w3l[j] = c3; }
}

// ht: f32 [64][128] with 16B-slot swizzle: slot(k>>2) ^= (row&7)
__device__ __forceinline__ void layer_mfma(
    const float* ht, const unsigned short* __restrict__ w1, const unsigned short* __restrict__ w2,
    const unsigned short* __restrict__ w3, const float* __restrict__ bias,
    f32x4 acc[2][4], int wr0, int wc0, int lm, int lg) {
    #pragma unroll
    for (int mt = 0; mt < 2; ++mt)
        #pragma unroll
        for (int nt = 0; nt < 4; ++nt) {
            float b = bias[wc0 + nt * 16 + lm];
            acc[mt][nt] = (f32x4){b, b, b, b};
        }
    for (int k0 = 0; k0 < 128; k0 += 32) {
        short8 a1[2], a2[2], a3[2];
        #pragma unroll
        for (int mt = 0; mt < 2; ++mt) {
            int row = wr0 + mt * 16 + lm;
            int kk = k0 + lg * 8;
            const float* base = ht + row * 128;
            int s = kk >> 2, key = row & 7;
            float4 x0 = *(const float4*)(base + ((s ^ key) << 2));
            float4 x1 = *(const float4*)(base + (((s + 1) ^ key) << 2));
            float xv[8] = {x0.x, x0.y, x0.z, x0.w, x1.x, x1.y, x1.z, x1.w};
            #pragma unroll
            for (int i = 0; i < 8; ++i) {
                float x = xv[i];
                unsigned short c1 = f2bf(x);
                float r = x - bf2f(c1);
                unsigned short c2 = f2bf(r);
                float r2 = r - bf2f(c2);
                unsigned short c3 = f2bf(r2);
                a1[mt][i] = (short)c1;
                a2[mt][i] = (short)c2;
                a3[mt][i] = (short)c3;
            }
        }
        #pragma unroll
        for (int nt = 0; nt < 4; ++nt) {
            int widx = (wc0 + nt * 16 + lm) * 128 + k0 + lg * 8;
            short8 b1 = *(const short8*)(w1 + widx);
            short8 b2 = *(const short8*)(w2 + widx);
            short8 b3 = *(const short8*)(w3 + widx);
            #pragma unroll
            for (int mt = 0; mt < 2; ++mt) {
                f32x4 c = acc[mt][nt];
                c = __builtin_amdgcn_mfma_f32_16x16x32_bf16(a1[mt], b1, c, 0, 0, 0);
                c = __builtin_amdgcn_mfma_f32_16x16x32_bf16(a1[mt], b2, c, 0, 0, 0);
                c = __builtin_amdgcn_mfma_f32_16x16x32_bf16(a2[mt], b1, c, 0, 0, 0);
                c = __builtin_amdgcn_mfma_f32_16x16x32_bf16(a1[mt], b3, c, 0, 0, 0);
                c = __builtin_amdgcn_mfma_f32_16x16x32_bf16(a2[mt], b2, c, 0, 0, 0);
                c = __builtin_amdgcn_mfma_f32_16x16x32_bf16(a3[mt], b1, c, 0, 0, 0);
                acc[mt][nt] = c;
            }
        }
    }
}

// write relu(acc) into swizzled ht (C layout: col=lane&15, row=(lane>>4)*4+reg)
__device__ __forceinline__ void store_tile(float* ht, f32x4 acc[2][4], int wr0, int wc0, int lm, int lg) {
    #pragma unroll
    for (int mt = 0; mt < 2; ++mt)
        #pragma unroll
        for (int nt = 0; nt < 4; ++nt)
            #pragma unroll
            for (int j = 0; j < 4; ++j) {
                int row = wr0 + mt * 16 + lg * 4 + j;
                int col = wc0 + nt * 16 + lm;
                ht[row * 128 + (((col >> 2) ^ (row & 7)) << 2) + (col & 3)] = fmaxf(acc[mt][nt][j], 0.0f);
            }
}

__global__ __launch_bounds__(256, 2) void mlp_mfma_kernel(
    const float* __restrict__ h2,
    const unsigned short* __restrict__ w1c, const unsigned short* __restrict__ w2c, const unsigned short* __restrict__ w3c,
    const float* __restrict__ bc,
    const unsigned short* __restrict__ w1l, const unsigned short* __restrict__ w2l, const unsigned short* __restrict__ w3l,
    const float* __restrict__ bl,
    float* __restrict__ out, int N) {
    __shared__ float ht[64 * 128];  // 32 KB, swizzled 16B slots
    int tid = threadIdx.x;
    int row0 = blockIdx.x * 64;

    // stage h2 (coalesced global float4 -> swizzled LDS; conflict-free)
    #pragma unroll
    for (int i = 0; i < 8; ++i) {
        int flat = (tid << 2) + (i << 10);
        int r = flat >> 7, k = flat & 127;
        int grow = row0 + r;
        float4 v = make_float4(0.f, 0.f, 0.f, 0.f);
        if (grow < N) v = *(const float4*)(h2 + (size_t)grow * D + k);
        *(float4*)(ht + r * 128 + (((k >> 2) ^ (r & 7)) << 2)) = v;
    }
    __syncthreads();

    int w = tid >> 6, lane = tid & 63;
    int lm = lane & 15, lg = lane >> 4;
    int wr0 = (w >> 1) * 32, wc0 = (w & 1) * 64;

    f32x4 acc[2][4];

    layer_mfma(ht, w1c, w2c, w3c, bc, acc, wr0, wc0, lm, lg);
    __syncthreads();                   // all reads of ht done
    store_tile(ht, acc, wr0, wc0, lm, lg);
    __syncthreads();

    layer_mfma(ht, w1l, w2l, w3l, bl, acc, wr0, wc0, lm, lg);
    __syncthreads();
    store_tile(ht, acc, wr0, wc0, lm, lg);
    __syncthreads();

    // coalesced copy-out
    #pragma unroll
    for (int i = 0; i < 8; ++i) {
        int flat = (tid << 2) + (i << 10);
        int r = flat >> 7, k = flat & 127;
        int grow = row0 + r;
        if (grow < N) {
            float4 v = *(const float4*)(ht + r * 128 + (((k >> 2) ^ (r & 7)) << 2));
            *(float4*)(out + (size_t)grow * D + k) = v;
        }
    }
}

extern "C" void kernel_launch(void* const* d_in, const int* in_sizes, int n_in,
                              void* d_out, int out_size, void* d_ws, size_t ws_size,
                              hipStream_t stream) {
    const float* x      = (const float*)d_in[0];
    const int*   src    = (const int*)d_in[1];
    const int*   dst    = (const int*)d_in[2];
    const float* wc     = (const float*)d_in[3];
    const float* bc     = (const float*)d_in[4];
    const float* wl     = (const float*)d_in[5];
    const float* bl     = (const float*)d_in[6];
    float* out = (float*)d_out;

    int N = in_sizes[0] / D;
    int E = in_sizes[1];

    // workspace carve-up (256B aligned)
    size_t off = 0;
    auto carve = [&](size_t bytes) -> void* {
        void* p = (char*)d_ws + off;
        off += (bytes + 255) & ~(size_t)255;
        return p;
    };
    float* xs        = (float*)carve((size_t)N * D * 4);
    float* h2        = (float*)carve((size_t)N * D * 4);
    int*   deg       = (int*)carve((size_t)N * 4);
    int*   row_start = (int*)carve((size_t)(N + 1) * 4);
    int*   cursor    = (int*)carve((size_t)N * 4);
    float* norm      = (float*)carve((size_t)N * 4);
    int*   blockSums = (int*)carve(1024 * 4);
    int*   sorted    = (int*)carve((size_t)E * 4);
    unsigned short* w1c = (unsigned short*)carve(16384 * 2);
    unsigned short* w2c = (unsigned short*)carve(16384 * 2);
    unsigned short* w3c = (unsigned short*)carve(16384 * 2);
    unsigned short* w1l = (unsigned short*)carve(16384 * 2);
    unsigned short* w2l = (unsigned short*)carve(16384 * 2);
    unsigned short* w3l = (unsigned short*)carve(16384 * 2);
    (void)ws_size;

    hipMemsetAsync(deg, 0, (size_t)N * 4, stream);

    int nScanBlocks = (N + SCAN_TILE - 1) / SCAN_TILE;

    prep_w_kernel<<<128, 256, 0, stream>>>(wc, wl, w1c, w2c, w3c, w1l, w2l, w3l);
    degree_kernel<<<(E / 4 + 255) / 256, 256, 0, stream>>>(dst, deg, E);
    scan_partial_kernel<<<nScanBlocks, 256, 0, stream>>>(deg, blockSums, N);
    scan_blocksums_kernel<<<1, 256, 0, stream>>>(blockSums, nScanBlocks);
    scan_final_kernel<<<nScanBlocks, 256, 0, stream>>>(deg, blockSums, row_start, cursor, norm, N, E);
    binning_kernel<<<(E / 4 + 255) / 256, 256, 0, stream>>>(src, dst, cursor, sorted, E);
    {
        int total = N * (D / 4);
        scale_kernel<<<(total + 255) / 256, 256, 0, stream>>>(x, norm, xs, N);
    }
    aggregate_kernel<<<(N + 3) / 4, 256, 0, stream>>>(xs, sorted, row_start, norm, h2, N);
    mlp_mfma_kernel<<<(N + 63) / 64, 256, 0, stream>>>(h2, w1c, w2c, w3c, bc, w1l, w2l, w3l, bl, out, N);
}

// Round 7
// 270.490 us; speedup vs baseline: 1.6972x; 1.0904x over previous
//
#include <hip/hip_runtime.h>

// SGConv (k=1) + Linear, fused pipeline:
//   1) deg[dst]++                   (histogram, int atomics, int4 edge reads)
//   2) exclusive scan(deg)          (3-phase multi-block scan; emits norm[])
//   3) counting-sort edges by dst   (atomic binning, int4 edge reads)
//   4) xs = x * norm                (stream pass, f32)
//   5) h2 = norm * sum_e xs[src_e]  (wave/node, float4 x 2-rows, no atomics)
//      -> h2 written PRE-SPLIT as bf16 hi/lo arrays
//   6) out = relu(relu(h2 @ Wc^T + bc) @ Wl^T + bl)   (MFMA, 2-way bf16 split:
//      3 products ~2^-17 rel err). A-frags = raw ds_read_b128 from bf16 LDS
//      tiles (swizzled); B-frags from pre-split weights in global (L2).

#define D 128
#define SCAN_TILE 1024  // 256 threads * 4 elements

typedef __attribute__((ext_vector_type(8))) short short8;
typedef __attribute__((ext_vector_type(4))) float f32x4;

__device__ __forceinline__ unsigned short f2bf(float f) {
    union { float f; unsigned u; } c; c.f = f;
    unsigned u = c.u;
    unsigned r = u + 0x7FFFu + ((u >> 16) & 1u);  // RNE
    return (unsigned short)(r >> 16);
}
__device__ __forceinline__ float bf2f(unsigned short b) {
    union { unsigned u; float f; } c; c.u = ((unsigned)b) << 16;
    return c.f;
}

__global__ void degree_kernel(const int* __restrict__ dst, int* __restrict__ deg, int E) {
    int i = (blockIdx.x * blockDim.x + threadIdx.x) << 2;
    if (i + 3 < E) {
        int4 d = *(const int4*)(dst + i);
        atomicAdd(&deg[d.x], 1);
        atomicAdd(&deg[d.y], 1);
        atomicAdd(&deg[d.z], 1);
        atomicAdd(&deg[d.w], 1);
    } else {
        for (int j = i; j < E; ++j) atomicAdd(&deg[dst[j]], 1);
    }
}

// ---- 3-phase exclusive scan over deg[0..N) -> row_start[0..N], cursor, norm ----
__global__ __launch_bounds__(256) void scan_partial_kernel(const int* __restrict__ deg,
                                                           int* __restrict__ blockSums, int N) {
    int tid = threadIdx.x;
    int base = blockIdx.x * SCAN_TILE + (tid << 2);
    int4 v = make_int4(0, 0, 0, 0);
    if (base + 3 < N) v = *(const int4*)(deg + base);
    else {
        if (base + 0 < N) v.x = deg[base + 0];
        if (base + 1 < N) v.y = deg[base + 1];
        if (base + 2 < N) v.z = deg[base + 2];
        if (base + 3 < N) v.w = deg[base + 3];
    }
    int s = v.x + v.y + v.z + v.w;
    for (int off = 32; off; off >>= 1) s += __shfl_down(s, off, 64);
    __shared__ int ws[4];
    if ((tid & 63) == 0) ws[tid >> 6] = s;
    __syncthreads();
    if (tid == 0) blockSums[blockIdx.x] = ws[0] + ws[1] + ws[2] + ws[3];
}

__global__ __launch_bounds__(256) void scan_blocksums_kernel(int* __restrict__ blockSums, int B) {
    __shared__ int s[256];
    int tid = threadIdx.x;
    int v = (tid < B) ? blockSums[tid] : 0;
    s[tid] = v;
    __syncthreads();
    for (int off = 1; off < 256; off <<= 1) {
        int u = (tid >= off) ? s[tid - off] : 0;
        __syncthreads();
        s[tid] += u;
        __syncthreads();
    }
    if (tid < B) blockSums[tid] = (tid == 0) ? 0 : s[tid - 1];
}

__global__ __launch_bounds__(256) void scan_final_kernel(
    const int* __restrict__ deg, const int* __restrict__ blockSums,
    int* __restrict__ row_start, int* __restrict__ cursor,
    float* __restrict__ norm, int N, int E) {
    int tid = threadIdx.x;
    int base = blockIdx.x * SCAN_TILE + (tid << 2);
    int4 v = make_int4(0, 0, 0, 0);
    if (base + 3 < N) v = *(const int4*)(deg + base);
    else {
        if (base + 0 < N) v.x = deg[base + 0];
        if (base + 1 < N) v.y = deg[base + 1];
        if (base + 2 < N) v.z = deg[base + 2];
        if (base + 3 < N) v.w = deg[base + 3];
    }
    int local = v.x + v.y + v.z + v.w;
    int lane = tid & 63, w = tid >> 6;
    int inc = local;
    for (int off = 1; off < 64; off <<= 1) {
        int u = __shfl_up(inc, off, 64);
        if (lane >= off) inc += u;
    }
    __shared__ int wsum[4];
    if (lane == 63) wsum[w] = inc;
    __syncthreads();
    int woff = 0;
    for (int i = 0; i < w; ++i) woff += wsum[i];
    int ex = (inc - local) + woff + blockSums[blockIdx.x];
    int4 rs;
    rs.x = ex;
    rs.y = rs.x + v.x;
    rs.z = rs.y + v.y;
    rs.w = rs.z + v.z;
    float4 nm;
    nm.x = rsqrtf(fmaxf((float)v.x, 1.0f));
    nm.y = rsqrtf(fmaxf((float)v.y, 1.0f));
    nm.z = rsqrtf(fmaxf((float)v.z, 1.0f));
    nm.w = rsqrtf(fmaxf((float)v.w, 1.0f));
    if (base + 3 < N) {
        *(int4*)(row_start + base) = rs;
        *(int4*)(cursor + base) = rs;
        *(float4*)(norm + base) = nm;
    } else {
        if (base + 0 < N) { row_start[base + 0] = rs.x; cursor[base + 0] = rs.x; norm[base + 0] = nm.x; }
        if (base + 1 < N) { row_start[base + 1] = rs.y; cursor[base + 1] = rs.y; norm[base + 1] = nm.y; }
        if (base + 2 < N) { row_start[base + 2] = rs.z; cursor[base + 2] = rs.z; norm[base + 2] = nm.z; }
    }
    if (blockIdx.x == 0 && tid == 0) row_start[N] = E;
}

__global__ void binning_kernel(const int* __restrict__ src, const int* __restrict__ dst,
                               int* __restrict__ cursor, int* __restrict__ sorted_src, int E) {
    int i = (blockIdx.x * blockDim.x + threadIdx.x) << 2;
    if (i + 3 < E) {
        int4 d = *(const int4*)(dst + i);
        int4 s = *(const int4*)(src + i);
        sorted_src[atomicAdd(&cursor[d.x], 1)] = s.x;
        sorted_src[atomicAdd(&cursor[d.y], 1)] = s.y;
        sorted_src[atomicAdd(&cursor[d.z], 1)] = s.z;
        sorted_src[atomicAdd(&cursor[d.w], 1)] = s.w;
    } else {
        for (int j = i; j < E; ++j) {
            int p = atomicAdd(&cursor[dst[j]], 1);
            sorted_src[p] = src[j];
        }
    }
}

// xs = x * norm[row]  (float4 over N*32)
__global__ void scale_kernel(const float* __restrict__ x, const float* __restrict__ norm,
                             float* __restrict__ xs, int N) {
    int idx = blockIdx.x * blockDim.x + threadIdx.x;
    int total = N * (D / 4);
    if (idx >= total) return;
    int row = idx >> 5;  // D/4 == 32
    float nrm = norm[row];
    float4 v = ((const float4*)x)[idx];
    v.x *= nrm; v.y *= nrm; v.z *= nrm; v.w *= nrm;
    ((float4*)xs)[idx] = v;
}

// wave per destination node; float4/lane, 2 rows per step; outputs pre-split bf16
__global__ __launch_bounds__(256) void aggregate_kernel(
    const float* __restrict__ xs, const int* __restrict__ sorted_src,
    const int* __restrict__ row_start, const float* __restrict__ norm,
    unsigned short* __restrict__ h2hi, unsigned short* __restrict__ h2lo, int N) {
    int wave = (int)((blockIdx.x * blockDim.x + threadIdx.x) >> 6);
    int lane = threadIdx.x & 63;
    if (wave >= N) return;
    int s = row_start[wave];
    int t = row_start[wave + 1];
    int c4 = (lane & 31) << 2;   // column offset (float4)
    int half = lane >> 5;        // which edge of the pair
    float4 acc = make_float4(0.f, 0.f, 0.f, 0.f);
    for (int base = s; base < t; base += 64) {
        int cnt = min(64, t - base);
        int my = (lane < cnt) ? sorted_src[base + lane] : 0;
        int j = 0;
        for (; j + 7 < cnt; j += 8) {  // 4 outstanding 16B loads / lane (8 rows / wave)
            int i0 = __shfl(my, j + 0 + half, 64);
            int i1 = __shfl(my, j + 2 + half, 64);
            int i2 = __shfl(my, j + 4 + half, 64);
            int i3 = __shfl(my, j + 6 + half, 64);
            float4 v0 = *(const float4*)(xs + (size_t)i0 * D + c4);
            float4 v1 = *(const float4*)(xs + (size_t)i1 * D + c4);
            float4 v2 = *(const float4*)(xs + (size_t)i2 * D + c4);
            float4 v3 = *(const float4*)(xs + (size_t)i3 * D + c4);
            acc.x += (v0.x + v1.x) + (v2.x + v3.x);
            acc.y += (v0.y + v1.y) + (v2.y + v3.y);
            acc.z += (v0.z + v1.z) + (v2.z + v3.z);
            acc.w += (v0.w + v1.w) + (v2.w + v3.w);
        }
        for (; j + 1 < cnt; j += 2) {
            int i0 = __shfl(my, j + half, 64);
            float4 v0 = *(const float4*)(xs + (size_t)i0 * D + c4);
            acc.x += v0.x; acc.y += v0.y; acc.z += v0.z; acc.w += v0.w;
        }
        if (j < cnt) {  // odd leftover edge: half 0 only
            int i0 = __shfl(my, j, 64);
            if (half == 0) {
                float4 v0 = *(const float4*)(xs + (size_t)i0 * D + c4);
                acc.x += v0.x; acc.y += v0.y; acc.z += v0.z; acc.w += v0.w;
            }
        }
    }
    // combine the two halves
    acc.x += __shfl_xor(acc.x, 32, 64);
    acc.y += __shfl_xor(acc.y, 32, 64);
    acc.z += __shfl_xor(acc.z, 32, 64);
    acc.w += __shfl_xor(acc.w, 32, 64);
    if (half == 0) {
        float nrm = norm[wave];
        float o[4] = {acc.x * nrm, acc.y * nrm, acc.z * nrm, acc.w * nrm};
        ushort4 hv, lv;
        unsigned short* hp = (unsigned short*)&hv;
        unsigned short* lp = (unsigned short*)&lv;
        #pragma unroll
        for (int q = 0; q < 4; ++q) {
            unsigned short h = f2bf(o[q]);
            float r = o[q] - bf2f(h);
            hp[q] = h;
            lp[q] = f2bf(r);
        }
        *(ushort4*)(h2hi + (size_t)wave * D + c4) = hv;
        *(ushort4*)(h2lo + (size_t)wave * D + c4) = lv;
    }
}

// ---------------- MFMA MLP (2-way split) ----------------
// weight prep: split each fp32 into hi/lo bf16
__global__ __launch_bounds__(256) void prep_w_kernel(
    const float* __restrict__ wc, const float* __restrict__ wl,
    unsigned short* __restrict__ w1c, unsigned short* __restrict__ w2c,
    unsigned short* __restrict__ w1l, unsigned short* __restrict__ w2l) {
    int idx = blockIdx.x * 256 + threadIdx.x;  // 0..32767
    const float* src = (idx < 16384) ? wc : wl;
    int j = idx & 16383;
    float x = src[j];
    unsigned short c1 = f2bf(x);
    float r = x - bf2f(c1);
    unsigned short c2 = f2bf(r);
    if (idx < 16384) { w1c[j] = c1; w2c[j] = c2; }
    else             { w1l[j] = c1; w2l[j] = c2; }
}

// LDS tiles: bf16 [64 rows][128], 16B slots swizzled: slot' = slot ^ (row&7)
__device__ __forceinline__ void layer_bf(
    const unsigned short* shi, const unsigned short* slo,
    const unsigned short* __restrict__ w1, const unsigned short* __restrict__ w2,
    const float* __restrict__ bias,
    f32x4 acc[2][4], int wr0, int wc0, int lm, int lg) {
    #pragma unroll
    for (int mt = 0; mt < 2; ++mt)
        #pragma unroll
        for (int nt = 0; nt < 4; ++nt) {
            float b = bias[wc0 + nt * 16 + lm];
            acc[mt][nt] = (f32x4){b, b, b, b};
        }
    #pragma unroll
    for (int k0 = 0; k0 < 128; k0 += 32) {
        short8 ahi[2], alo[2];
        #pragma unroll
        for (int mt = 0; mt < 2; ++mt) {
            int row = wr0 + mt * 16 + lm;
            int slot = (k0 >> 3) + lg;
            int off = row * 128 + (((slot) ^ (row & 7)) << 3);
            ahi[mt] = *(const short8*)(shi + off);
            alo[mt] = *(const short8*)(slo + off);
        }
        #pragma unroll
        for (int nt = 0; nt < 4; ++nt) {
            int widx = (wc0 + nt * 16 + lm) * 128 + k0 + lg * 8;
            short8 bhi = *(const short8*)(w1 + widx);
            short8 blo = *(const short8*)(w2 + widx);
            #pragma unroll
            for (int mt = 0; mt < 2; ++mt) {
                f32x4 c = acc[mt][nt];
                c = __builtin_amdgcn_mfma_f32_16x16x32_bf16(ahi[mt], blo, c, 0, 0, 0);
                c = __builtin_amdgcn_mfma_f32_16x16x32_bf16(alo[mt], bhi, c, 0, 0, 0);
                c = __builtin_amdgcn_mfma_f32_16x16x32_bf16(ahi[mt], bhi, c, 0, 0, 0);
                acc[mt][nt] = c;
            }
        }
    }
}

// relu + split into swizzled bf16 LDS (C layout: col=lane&15, row=(lane>>4)*4+reg)
__device__ __forceinline__ void store_bf(
    unsigned short* shi, unsigned short* slo,
    f32x4 acc[2][4], int wr0, int wc0, int lm, int lg) {
    #pragma unroll
    for (int mt = 0; mt < 2; ++mt)
        #pragma unroll
        for (int nt = 0; nt < 4; ++nt)
            #pragma unroll
            for (int j = 0; j < 4; ++j) {
                int row = wr0 + mt * 16 + lg * 4 + j;
                int col = wc0 + nt * 16 + lm;
                float v = fmaxf(acc[mt][nt][j], 0.0f);
                unsigned short h = f2bf(v);
                float r = v - bf2f(h);
                int off = row * 128 + (((col >> 3) ^ (row & 7)) << 3) + (col & 7);
                shi[off] = h;
                slo[off] = f2bf(r);
            }
}

__global__ __launch_bounds__(256, 2) void mlp_mfma_kernel(
    const unsigned short* __restrict__ h2hi, const unsigned short* __restrict__ h2lo,
    const unsigned short* __restrict__ w1c, const unsigned short* __restrict__ w2c,
    const float* __restrict__ bc,
    const unsigned short* __restrict__ w1l, const unsigned short* __restrict__ w2l,
    const float* __restrict__ bl,
    float* __restrict__ out, int N) {
    __shared__ unsigned short shi[64 * 128];  // 16 KB
    __shared__ unsigned short slo[64 * 128];  // 16 KB
    int tid = threadIdx.x;
    int row0 = blockIdx.x * 64;

    // stage pre-split h2 (coalesced 16B global loads -> swizzled LDS slots)
    #pragma unroll
    for (int i = 0; i < 4; ++i) {
        int f = i * 256 + tid;            // slot id 0..1023
        int r = f >> 4, sl = f & 15;
        int grow = row0 + r;
        short8 vh = (short8){0,0,0,0,0,0,0,0};
        short8 vl = (short8){0,0,0,0,0,0,0,0};
        if (grow < N) {
            vh = *(const short8*)(h2hi + (size_t)grow * D + sl * 8);
            vl = *(const short8*)(h2lo + (size_t)grow * D + sl * 8);
        }
        int off = r * 128 + ((sl ^ (r & 7)) << 3);
        *(short8*)(shi + off) = vh;
        *(short8*)(slo + off) = vl;
    }
    __syncthreads();

    int w = tid >> 6, lane = tid & 63;
    int lm = lane & 15, lg = lane >> 4;
    int wr0 = (w >> 1) * 32, wc0 = (w & 1) * 64;

    f32x4 acc[2][4];

    layer_bf(shi, slo, w1c, w2c, bc, acc, wr0, wc0, lm, lg);
    __syncthreads();                   // all reads of tiles done
    store_bf(shi, slo, acc, wr0, wc0, lm, lg);
    __syncthreads();

    layer_bf(shi, slo, w1l, w2l, bl, acc, wr0, wc0, lm, lg);

    // direct relu + store to global (64B-granular coalescing per 16-lane group)
    #pragma unroll
    for (int mt = 0; mt < 2; ++mt)
        #pragma unroll
        for (int j = 0; j < 4; ++j) {
            int row = row0 + wr0 + mt * 16 + lg * 4 + j;
            if (row < N) {
                #pragma unroll
                for (int nt = 0; nt < 4; ++nt)
                    out[(size_t)row * D + wc0 + nt * 16 + lm] = fmaxf(acc[mt][nt][j], 0.0f);
            }
        }
}

extern "C" void kernel_launch(void* const* d_in, const int* in_sizes, int n_in,
                              void* d_out, int out_size, void* d_ws, size_t ws_size,
                              hipStream_t stream) {
    const float* x      = (const float*)d_in[0];
    const int*   src    = (const int*)d_in[1];
    const int*   dst    = (const int*)d_in[2];
    const float* wc     = (const float*)d_in[3];
    const float* bc     = (const float*)d_in[4];
    const float* wl     = (const float*)d_in[5];
    const float* bl     = (const float*)d_in[6];
    float* out = (float*)d_out;

    int N = in_sizes[0] / D;
    int E = in_sizes[1];

    // workspace carve-up (256B aligned)
    size_t off = 0;
    auto carve = [&](size_t bytes) -> void* {
        void* p = (char*)d_ws + off;
        off += (bytes + 255) & ~(size_t)255;
        return p;
    };
    float*          xs        = (float*)carve((size_t)N * D * 4);
    unsigned short* h2hi      = (unsigned short*)carve((size_t)N * D * 2);
    unsigned short* h2lo      = (unsigned short*)carve((size_t)N * D * 2);
    int*            deg       = (int*)carve((size_t)N * 4);
    int*            row_start = (int*)carve((size_t)(N + 1) * 4);
    int*            cursor    = (int*)carve((size_t)N * 4);
    float*          norm      = (float*)carve((size_t)N * 4);
    int*            blockSums = (int*)carve(1024 * 4);
    int*            sorted    = (int*)carve((size_t)E * 4);
    unsigned short* w1c = (unsigned short*)carve(16384 * 2);
    unsigned short* w2c = (unsigned short*)carve(16384 * 2);
    unsigned short* w1l = (unsigned short*)carve(16384 * 2);
    unsigned short* w2l = (unsigned short*)carve(16384 * 2);
    (void)ws_size;

    hipMemsetAsync(deg, 0, (size_t)N * 4, stream);

    int nScanBlocks = (N + SCAN_TILE - 1) / SCAN_TILE;

    prep_w_kernel<<<128, 256, 0, stream>>>(wc, wl, w1c, w2c, w1l, w2l);
    degree_kernel<<<(E / 4 + 255) / 256, 256, 0, stream>>>(dst, deg, E);
    scan_partial_kernel<<<nScanBlocks, 256, 0, stream>>>(deg, blockSums, N);
    scan_blocksums_kernel<<<1, 256, 0, stream>>>(blockSums, nScanBlocks);
    scan_final_kernel<<<nScanBlocks, 256, 0, stream>>>(deg, blockSums, row_start, cursor, norm, N, E);
    binning_kernel<<<(E / 4 + 255) / 256, 256, 0, stream>>>(src, dst, cursor, sorted, E);
    {
        int total = N * (D / 4);
        scale_kernel<<<(total + 255) / 256, 256, 0, stream>>>(x, norm, xs, N);
    }
    aggregate_kernel<<<(N + 3) / 4, 256, 0, stream>>>(xs, sorted, row_start, norm, h2hi, h2lo, N);
    mlp_mfma_kernel<<<(N + 63) / 64, 256, 0, stream>>>(h2hi, h2lo, w1c, w2c, bc, w1l, w2l, bl, out, N);
}

// Round 8
// 249.482 us; speedup vs baseline: 1.8401x; 1.0842x over previous
//
#include <hip/hip_runtime.h>

// SGConv (k=1) + Linear, fused pipeline:
//   1) deg[dst]++                   (histogram, int atomics, int4 edge reads)
//   2) exclusive scan(deg)          (3-phase multi-block scan; emits norm[])
//   3) counting-sort edges by dst   (atomic binning, int4 edge reads)
//   4) xs = bf16(x * norm)          (stream pass; HALVES the gather payload)
//   5) h2 = norm * sum_e xs[src_e]  (wave/node, bf16 gather + fp32 accum)
//      -> h2 written PRE-SPLIT as bf16 hi/lo arrays
//   6) out = relu(relu(h2 @ Wc^T + bc) @ Wl^T + bl)   (MFMA, 2-way bf16 split)

#define D 128
#define SCAN_TILE 1024  // 256 threads * 4 elements

typedef __attribute__((ext_vector_type(8))) short short8;
typedef __attribute__((ext_vector_type(4))) float f32x4;

__device__ __forceinline__ unsigned short f2bf(float f) {
    union { float f; unsigned u; } c; c.f = f;
    unsigned u = c.u;
    unsigned r = u + 0x7FFFu + ((u >> 16) & 1u);  // RNE
    return (unsigned short)(r >> 16);
}
__device__ __forceinline__ float bf2f(unsigned short b) {
    union { unsigned u; float f; } c; c.u = ((unsigned)b) << 16;
    return c.f;
}

__global__ void degree_kernel(const int* __restrict__ dst, int* __restrict__ deg, int E) {
    int i = (blockIdx.x * blockDim.x + threadIdx.x) << 2;
    if (i + 3 < E) {
        int4 d = *(const int4*)(dst + i);
        atomicAdd(&deg[d.x], 1);
        atomicAdd(&deg[d.y], 1);
        atomicAdd(&deg[d.z], 1);
        atomicAdd(&deg[d.w], 1);
    } else {
        for (int j = i; j < E; ++j) atomicAdd(&deg[dst[j]], 1);
    }
}

// ---- 3-phase exclusive scan over deg[0..N) -> row_start[0..N], cursor, norm ----
__global__ __launch_bounds__(256) void scan_partial_kernel(const int* __restrict__ deg,
                                                           int* __restrict__ blockSums, int N) {
    int tid = threadIdx.x;
    int base = blockIdx.x * SCAN_TILE + (tid << 2);
    int4 v = make_int4(0, 0, 0, 0);
    if (base + 3 < N) v = *(const int4*)(deg + base);
    else {
        if (base + 0 < N) v.x = deg[base + 0];
        if (base + 1 < N) v.y = deg[base + 1];
        if (base + 2 < N) v.z = deg[base + 2];
        if (base + 3 < N) v.w = deg[base + 3];
    }
    int s = v.x + v.y + v.z + v.w;
    for (int off = 32; off; off >>= 1) s += __shfl_down(s, off, 64);
    __shared__ int ws[4];
    if ((tid & 63) == 0) ws[tid >> 6] = s;
    __syncthreads();
    if (tid == 0) blockSums[blockIdx.x] = ws[0] + ws[1] + ws[2] + ws[3];
}

__global__ __launch_bounds__(256) void scan_blocksums_kernel(int* __restrict__ blockSums, int B) {
    __shared__ int s[256];
    int tid = threadIdx.x;
    int v = (tid < B) ? blockSums[tid] : 0;
    s[tid] = v;
    __syncthreads();
    for (int off = 1; off < 256; off <<= 1) {
        int u = (tid >= off) ? s[tid - off] : 0;
        __syncthreads();
        s[tid] += u;
        __syncthreads();
    }
    if (tid < B) blockSums[tid] = (tid == 0) ? 0 : s[tid - 1];
}

__global__ __launch_bounds__(256) void scan_final_kernel(
    const int* __restrict__ deg, const int* __restrict__ blockSums,
    int* __restrict__ row_start, int* __restrict__ cursor,
    float* __restrict__ norm, int N, int E) {
    int tid = threadIdx.x;
    int base = blockIdx.x * SCAN_TILE + (tid << 2);
    int4 v = make_int4(0, 0, 0, 0);
    if (base + 3 < N) v = *(const int4*)(deg + base);
    else {
        if (base + 0 < N) v.x = deg[base + 0];
        if (base + 1 < N) v.y = deg[base + 1];
        if (base + 2 < N) v.z = deg[base + 2];
        if (base + 3 < N) v.w = deg[base + 3];
    }
    int local = v.x + v.y + v.z + v.w;
    int lane = tid & 63, w = tid >> 6;
    int inc = local;
    for (int off = 1; off < 64; off <<= 1) {
        int u = __shfl_up(inc, off, 64);
        if (lane >= off) inc += u;
    }
    __shared__ int wsum[4];
    if (lane == 63) wsum[w] = inc;
    __syncthreads();
    int woff = 0;
    for (int i = 0; i < w; ++i) woff += wsum[i];
    int ex = (inc - local) + woff + blockSums[blockIdx.x];
    int4 rs;
    rs.x = ex;
    rs.y = rs.x + v.x;
    rs.z = rs.y + v.y;
    rs.w = rs.z + v.z;
    float4 nm;
    nm.x = rsqrtf(fmaxf((float)v.x, 1.0f));
    nm.y = rsqrtf(fmaxf((float)v.y, 1.0f));
    nm.z = rsqrtf(fmaxf((float)v.z, 1.0f));
    nm.w = rsqrtf(fmaxf((float)v.w, 1.0f));
    if (base + 3 < N) {
        *(int4*)(row_start + base) = rs;
        *(int4*)(cursor + base) = rs;
        *(float4*)(norm + base) = nm;
    } else {
        if (base + 0 < N) { row_start[base + 0] = rs.x; cursor[base + 0] = rs.x; norm[base + 0] = nm.x; }
        if (base + 1 < N) { row_start[base + 1] = rs.y; cursor[base + 1] = rs.y; norm[base + 1] = nm.y; }
        if (base + 2 < N) { row_start[base + 2] = rs.z; cursor[base + 2] = rs.z; norm[base + 2] = nm.z; }
    }
    if (blockIdx.x == 0 && tid == 0) row_start[N] = E;
}

__global__ void binning_kernel(const int* __restrict__ src, const int* __restrict__ dst,
                               int* __restrict__ cursor, int* __restrict__ sorted_src, int E) {
    int i = (blockIdx.x * blockDim.x + threadIdx.x) << 2;
    if (i + 3 < E) {
        int4 d = *(const int4*)(dst + i);
        int4 s = *(const int4*)(src + i);
        sorted_src[atomicAdd(&cursor[d.x], 1)] = s.x;
        sorted_src[atomicAdd(&cursor[d.y], 1)] = s.y;
        sorted_src[atomicAdd(&cursor[d.z], 1)] = s.z;
        sorted_src[atomicAdd(&cursor[d.w], 1)] = s.w;
    } else {
        for (int j = i; j < E; ++j) {
            int p = atomicAdd(&cursor[dst[j]], 1);
            sorted_src[p] = src[j];
        }
    }
}

// xs = bf16(x * norm[row])  (reads float4, writes ushort4 = 8B/lane)
__global__ void scale_kernel(const float* __restrict__ x, const float* __restrict__ norm,
                             unsigned short* __restrict__ xsb, int N) {
    int idx = blockIdx.x * blockDim.x + threadIdx.x;
    int total = N * (D / 4);
    if (idx >= total) return;
    int row = idx >> 5;  // D/4 == 32
    float nrm = norm[row];
    float4 v = ((const float4*)x)[idx];
    ushort4 o;
    o.x = f2bf(v.x * nrm);
    o.y = f2bf(v.y * nrm);
    o.z = f2bf(v.z * nrm);
    o.w = f2bf(v.w * nrm);
    ((ushort4*)xsb)[idx] = o;
}

__device__ __forceinline__ void addbf4(float4& a, ushort4 u) {
    a.x += bf2f(u.x);
    a.y += bf2f(u.y);
    a.z += bf2f(u.z);
    a.w += bf2f(u.w);
}

// wave per destination node; bf16 gather (256B/row), fp32 accum; 2 rows in
// flight via lane-halves, 8 outstanding 8B loads/lane; outputs pre-split bf16
__global__ __launch_bounds__(256) void aggregate_kernel(
    const unsigned short* __restrict__ xsb, const int* __restrict__ sorted_src,
    const int* __restrict__ row_start, const float* __restrict__ norm,
    unsigned short* __restrict__ h2hi, unsigned short* __restrict__ h2lo, int N) {
    int wave = (int)((blockIdx.x * blockDim.x + threadIdx.x) >> 6);
    int lane = threadIdx.x & 63;
    if (wave >= N) return;
    int s = row_start[wave];
    int t = row_start[wave + 1];
    int c4 = (lane & 31) << 2;   // element column (4 bf16 per lane)
    int half = lane >> 5;        // which edge of the pair
    float4 acc = make_float4(0.f, 0.f, 0.f, 0.f);
    for (int base = s; base < t; base += 64) {
        int cnt = min(64, t - base);
        int my = (lane < cnt) ? sorted_src[base + lane] : 0;
        int j = 0;
        for (; j + 15 < cnt; j += 16) {  // 8 outstanding 8B loads per lane
            int i0 = __shfl(my, j + 0 + half, 64);
            int i1 = __shfl(my, j + 2 + half, 64);
            int i2 = __shfl(my, j + 4 + half, 64);
            int i3 = __shfl(my, j + 6 + half, 64);
            int i4 = __shfl(my, j + 8 + half, 64);
            int i5 = __shfl(my, j + 10 + half, 64);
            int i6 = __shfl(my, j + 12 + half, 64);
            int i7 = __shfl(my, j + 14 + half, 64);
            ushort4 u0 = *(const ushort4*)(xsb + (size_t)i0 * D + c4);
            ushort4 u1 = *(const ushort4*)(xsb + (size_t)i1 * D + c4);
            ushort4 u2 = *(const ushort4*)(xsb + (size_t)i2 * D + c4);
            ushort4 u3 = *(const ushort4*)(xsb + (size_t)i3 * D + c4);
            ushort4 u4 = *(const ushort4*)(xsb + (size_t)i4 * D + c4);
            ushort4 u5 = *(const ushort4*)(xsb + (size_t)i5 * D + c4);
            ushort4 u6 = *(const ushort4*)(xsb + (size_t)i6 * D + c4);
            ushort4 u7 = *(const ushort4*)(xsb + (size_t)i7 * D + c4);
            addbf4(acc, u0); addbf4(acc, u1); addbf4(acc, u2); addbf4(acc, u3);
            addbf4(acc, u4); addbf4(acc, u5); addbf4(acc, u6); addbf4(acc, u7);
        }
        for (; j + 1 < cnt; j += 2) {
            int i0 = __shfl(my, j + half, 64);
            ushort4 u0 = *(const ushort4*)(xsb + (size_t)i0 * D + c4);
            addbf4(acc, u0);
        }
        if (j < cnt) {  // odd leftover edge: half 0 only
            int i0 = __shfl(my, j, 64);
            if (half == 0) {
                ushort4 u0 = *(const ushort4*)(xsb + (size_t)i0 * D + c4);
                addbf4(acc, u0);
            }
        }
    }
    // combine the two halves
    acc.x += __shfl_xor(acc.x, 32, 64);
    acc.y += __shfl_xor(acc.y, 32, 64);
    acc.z += __shfl_xor(acc.z, 32, 64);
    acc.w += __shfl_xor(acc.w, 32, 64);
    if (half == 0) {
        float nrm = norm[wave];
        float o[4] = {acc.x * nrm, acc.y * nrm, acc.z * nrm, acc.w * nrm};
        ushort4 hv, lv;
        unsigned short* hp = (unsigned short*)&hv;
        unsigned short* lp = (unsigned short*)&lv;
        #pragma unroll
        for (int q = 0; q < 4; ++q) {
            unsigned short h = f2bf(o[q]);
            float r = o[q] - bf2f(h);
            hp[q] = h;
            lp[q] = f2bf(r);
        }
        *(ushort4*)(h2hi + (size_t)wave * D + c4) = hv;
        *(ushort4*)(h2lo + (size_t)wave * D + c4) = lv;
    }
}

// ---------------- MFMA MLP (2-way split) ----------------
// weight prep: split each fp32 into hi/lo bf16
__global__ __launch_bounds__(256) void prep_w_kernel(
    const float* __restrict__ wc, const float* __restrict__ wl,
    unsigned short* __restrict__ w1c, unsigned short* __restrict__ w2c,
    unsigned short* __restrict__ w1l, unsigned short* __restrict__ w2l) {
    int idx = blockIdx.x * 256 + threadIdx.x;  // 0..32767
    const float* src = (idx < 16384) ? wc : wl;
    int j = idx & 16383;
    float x = src[j];
    unsigned short c1 = f2bf(x);
    float r = x - bf2f(c1);
    unsigned short c2 = f2bf(r);
    if (idx < 16384) { w1c[j] = c1; w2c[j] = c2; }
    else             { w1l[j] = c1; w2l[j] = c2; }
}

// LDS tiles: bf16 [64 rows][128], 16B slots swizzled: slot' = slot ^ (row&7)
__device__ __forceinline__ void layer_bf(
    const unsigned short* shi, const unsigned short* slo,
    const unsigned short* __restrict__ w1, const unsigned short* __restrict__ w2,
    const float* __restrict__ bias,
    f32x4 acc[2][4], int wr0, int wc0, int lm, int lg) {
    #pragma unroll
    for (int mt = 0; mt < 2; ++mt)
        #pragma unroll
        for (int nt = 0; nt < 4; ++nt) {
            float b = bias[wc0 + nt * 16 + lm];
            acc[mt][nt] = (f32x4){b, b, b, b};
        }
    #pragma unroll
    for (int k0 = 0; k0 < 128; k0 += 32) {
        short8 ahi[2], alo[2];
        #pragma unroll
        for (int mt = 0; mt < 2; ++mt) {
            int row = wr0 + mt * 16 + lm;
            int slot = (k0 >> 3) + lg;
            int off = row * 128 + (((slot) ^ (row & 7)) << 3);
            ahi[mt] = *(const short8*)(shi + off);
            alo[mt] = *(const short8*)(slo + off);
        }
        #pragma unroll
        for (int nt = 0; nt < 4; ++nt) {
            int widx = (wc0 + nt * 16 + lm) * 128 + k0 + lg * 8;
            short8 bhi = *(const short8*)(w1 + widx);
            short8 blo = *(const short8*)(w2 + widx);
            #pragma unroll
            for (int mt = 0; mt < 2; ++mt) {
                f32x4 c = acc[mt][nt];
                c = __builtin_amdgcn_mfma_f32_16x16x32_bf16(ahi[mt], blo, c, 0, 0, 0);
                c = __builtin_amdgcn_mfma_f32_16x16x32_bf16(alo[mt], bhi, c, 0, 0, 0);
                c = __builtin_amdgcn_mfma_f32_16x16x32_bf16(ahi[mt], bhi, c, 0, 0, 0);
                acc[mt][nt] = c;
            }
        }
    }
}

// relu + split into swizzled bf16 LDS (C layout: col=lane&15, row=(lane>>4)*4+reg)
__device__ __forceinline__ void store_bf(
    unsigned short* shi, unsigned short* slo,
    f32x4 acc[2][4], int wr0, int wc0, int lm, int lg) {
    #pragma unroll
    for (int mt = 0; mt < 2; ++mt)
        #pragma unroll
        for (int nt = 0; nt < 4; ++nt)
            #pragma unroll
            for (int j = 0; j < 4; ++j) {
                int row = wr0 + mt * 16 + lg * 4 + j;
                int col = wc0 + nt * 16 + lm;
                float v = fmaxf(acc[mt][nt][j], 0.0f);
                unsigned short h = f2bf(v);
                float r = v - bf2f(h);
                int off = row * 128 + (((col >> 3) ^ (row & 7)) << 3) + (col & 7);
                shi[off] = h;
                slo[off] = f2bf(r);
            }
}

__global__ __launch_bounds__(256, 2) void mlp_mfma_kernel(
    const unsigned short* __restrict__ h2hi, const unsigned short* __restrict__ h2lo,
    const unsigned short* __restrict__ w1c, const unsigned short* __restrict__ w2c,
    const float* __restrict__ bc,
    const unsigned short* __restrict__ w1l, const unsigned short* __restrict__ w2l,
    const float* __restrict__ bl,
    float* __restrict__ out, int N) {
    __shared__ unsigned short shi[64 * 128];  // 16 KB
    __shared__ unsigned short slo[64 * 128];  // 16 KB
    int tid = threadIdx.x;
    int row0 = blockIdx.x * 64;

    // stage pre-split h2 (coalesced 16B global loads -> swizzled LDS slots)
    #pragma unroll
    for (int i = 0; i < 4; ++i) {
        int f = i * 256 + tid;            // slot id 0..1023
        int r = f >> 4, sl = f & 15;
        int grow = row0 + r;
        short8 vh = (short8){0,0,0,0,0,0,0,0};
        short8 vl = (short8){0,0,0,0,0,0,0,0};
        if (grow < N) {
            vh = *(const short8*)(h2hi + (size_t)grow * D + sl * 8);
            vl = *(const short8*)(h2lo + (size_t)grow * D + sl * 8);
        }
        int off = r * 128 + ((sl ^ (r & 7)) << 3);
        *(short8*)(shi + off) = vh;
        *(short8*)(slo + off) = vl;
    }
    __syncthreads();

    int w = tid >> 6, lane = tid & 63;
    int lm = lane & 15, lg = lane >> 4;
    int wr0 = (w >> 1) * 32, wc0 = (w & 1) * 64;

    f32x4 acc[2][4];

    layer_bf(shi, slo, w1c, w2c, bc, acc, wr0, wc0, lm, lg);
    __syncthreads();                   // all reads of tiles done
    store_bf(shi, slo, acc, wr0, wc0, lm, lg);
    __syncthreads();

    layer_bf(shi, slo, w1l, w2l, bl, acc, wr0, wc0, lm, lg);

    // direct relu + store to global (64B-granular coalescing per 16-lane group)
    #pragma unroll
    for (int mt = 0; mt < 2; ++mt)
        #pragma unroll
        for (int j = 0; j < 4; ++j) {
            int row = row0 + wr0 + mt * 16 + lg * 4 + j;
            if (row < N) {
                #pragma unroll
                for (int nt = 0; nt < 4; ++nt)
                    out[(size_t)row * D + wc0 + nt * 16 + lm] = fmaxf(acc[mt][nt][j], 0.0f);
            }
        }
}

extern "C" void kernel_launch(void* const* d_in, const int* in_sizes, int n_in,
                              void* d_out, int out_size, void* d_ws, size_t ws_size,
                              hipStream_t stream) {
    const float* x      = (const float*)d_in[0];
    const int*   src    = (const int*)d_in[1];
    const int*   dst    = (const int*)d_in[2];
    const float* wc     = (const float*)d_in[3];
    const float* bc     = (const float*)d_in[4];
    const float* wl     = (const float*)d_in[5];
    const float* bl     = (const float*)d_in[6];
    float* out = (float*)d_out;

    int N = in_sizes[0] / D;
    int E = in_sizes[1];

    // workspace carve-up (256B aligned)
    size_t off = 0;
    auto carve = [&](size_t bytes) -> void* {
        void* p = (char*)d_ws + off;
        off += (bytes + 255) & ~(size_t)255;
        return p;
    };
    unsigned short* xsb       = (unsigned short*)carve((size_t)N * D * 2);
    unsigned short* h2hi      = (unsigned short*)carve((size_t)N * D * 2);
    unsigned short* h2lo      = (unsigned short*)carve((size_t)N * D * 2);
    int*            deg       = (int*)carve((size_t)N * 4);
    int*            row_start = (int*)carve((size_t)(N + 1) * 4);
    int*            cursor    = (int*)carve((size_t)N * 4);
    float*          norm      = (float*)carve((size_t)N * 4);
    int*            blockSums = (int*)carve(1024 * 4);
    int*            sorted    = (int*)carve((size_t)E * 4);
    unsigned short* w1c = (unsigned short*)carve(16384 * 2);
    unsigned short* w2c = (unsigned short*)carve(16384 * 2);
    unsigned short* w1l = (unsigned short*)carve(16384 * 2);
    unsigned short* w2l = (unsigned short*)carve(16384 * 2);
    (void)ws_size;

    hipMemsetAsync(deg, 0, (size_t)N * 4, stream);

    int nScanBlocks = (N + SCAN_TILE - 1) / SCAN_TILE;

    prep_w_kernel<<<128, 256, 0, stream>>>(wc, wl, w1c, w2c, w1l, w2l);
    degree_kernel<<<(E / 4 + 255) / 256, 256, 0, stream>>>(dst, deg, E);
    scan_partial_kernel<<<nScanBlocks, 256, 0, stream>>>(deg, blockSums, N);
    scan_blocksums_kernel<<<1, 256, 0, stream>>>(blockSums, nScanBlocks);
    scan_final_kernel<<<nScanBlocks, 256, 0, stream>>>(deg, blockSums, row_start, cursor, norm, N, E);
    binning_kernel<<<(E / 4 + 255) / 256, 256, 0, stream>>>(src, dst, cursor, sorted, E);
    {
        int total = N * (D / 4);
        scale_kernel<<<(total + 255) / 256, 256, 0, stream>>>(x, norm, xsb, N);
    }
    aggregate_kernel<<<(N + 3) / 4, 256, 0, stream>>>(xsb, sorted, row_start, norm, h2hi, h2lo, N);
    mlp_mfma_kernel<<<(N + 63) / 64, 256, 0, stream>>>(h2hi, h2lo, w1c, w2c, bc, w1l, w2l, bl, out, N);
}

// Round 9
// 244.219 us; speedup vs baseline: 1.8797x; 1.0216x over previous
//
#include <hip/hip_runtime.h>

// SGConv (k=1) + Linear, fused pipeline:
//   1) deg[dst]++                   (histogram, 1 edge/thread, full occupancy)
//   2) exclusive scan(deg)          (3-phase multi-block scan; emits norm[])
//   3) counting-sort edges by dst   (1 edge/thread, u16 payload)
//   4) xs = bf16(x * norm)          (stream pass)
//   5) h2 = norm * sum_e xs[src_e]  (wave/node, bf16 gather + fp32 accum)
//      -> h2 written PRE-SPLIT as bf16 hi/lo arrays
//   6) out = relu(relu(h2 @ Wc^T + bc) @ Wl^T + bl)   (MFMA, 2-way bf16 split)

#define D 128
#define SCAN_TILE 1024  // 256 threads * 4 elements

typedef __attribute__((ext_vector_type(8))) short short8;
typedef __attribute__((ext_vector_type(4))) float f32x4;

__device__ __forceinline__ unsigned short f2bf(float f) {
    union { float f; unsigned u; } c; c.f = f;
    unsigned u = c.u;
    unsigned r = u + 0x7FFFu + ((u >> 16) & 1u);  // RNE
    return (unsigned short)(r >> 16);
}
__device__ __forceinline__ float bf2f(unsigned short b) {
    union { unsigned u; float f; } c; c.u = ((unsigned)b) << 16;
    return c.f;
}

// 1 edge/thread: maximize independent atomic chains in flight (latency-bound)
__global__ __launch_bounds__(256) void degree_kernel(const int* __restrict__ dst,
                                                     int* __restrict__ deg, int E) {
    int e = blockIdx.x * blockDim.x + threadIdx.x;
    if (e < E) atomicAdd(&deg[dst[e]], 1);
}

// ---- 3-phase exclusive scan over deg[0..N) -> row_start[0..N], cursor, norm ----
__global__ __launch_bounds__(256) void scan_partial_kernel(const int* __restrict__ deg,
                                                           int* __restrict__ blockSums, int N) {
    int tid = threadIdx.x;
    int base = blockIdx.x * SCAN_TILE + (tid << 2);
    int4 v = make_int4(0, 0, 0, 0);
    if (base + 3 < N) v = *(const int4*)(deg + base);
    else {
        if (base + 0 < N) v.x = deg[base + 0];
        if (base + 1 < N) v.y = deg[base + 1];
        if (base + 2 < N) v.z = deg[base + 2];
        if (base + 3 < N) v.w = deg[base + 3];
    }
    int s = v.x + v.y + v.z + v.w;
    for (int off = 32; off; off >>= 1) s += __shfl_down(s, off, 64);
    __shared__ int ws[4];
    if ((tid & 63) == 0) ws[tid >> 6] = s;
    __syncthreads();
    if (tid == 0) blockSums[blockIdx.x] = ws[0] + ws[1] + ws[2] + ws[3];
}

__global__ __launch_bounds__(256) void scan_blocksums_kernel(int* __restrict__ blockSums, int B) {
    __shared__ int s[256];
    int tid = threadIdx.x;
    int v = (tid < B) ? blockSums[tid] : 0;
    s[tid] = v;
    __syncthreads();
    for (int off = 1; off < 256; off <<= 1) {
        int u = (tid >= off) ? s[tid - off] : 0;
        __syncthreads();
        s[tid] += u;
        __syncthreads();
    }
    if (tid < B) blockSums[tid] = (tid == 0) ? 0 : s[tid - 1];
}

__global__ __launch_bounds__(256) void scan_final_kernel(
    const int* __restrict__ deg, const int* __restrict__ blockSums,
    int* __restrict__ row_start, int* __restrict__ cursor,
    float* __restrict__ norm, int N, int E) {
    int tid = threadIdx.x;
    int base = blockIdx.x * SCAN_TILE + (tid << 2);
    int4 v = make_int4(0, 0, 0, 0);
    if (base + 3 < N) v = *(const int4*)(deg + base);
    else {
        if (base + 0 < N) v.x = deg[base + 0];
        if (base + 1 < N) v.y = deg[base + 1];
        if (base + 2 < N) v.z = deg[base + 2];
        if (base + 3 < N) v.w = deg[base + 3];
    }
    int local = v.x + v.y + v.z + v.w;
    int lane = tid & 63, w = tid >> 6;
    int inc = local;
    for (int off = 1; off < 64; off <<= 1) {
        int u = __shfl_up(inc, off, 64);
        if (lane >= off) inc += u;
    }
    __shared__ int wsum[4];
    if (lane == 63) wsum[w] = inc;
    __syncthreads();
    int woff = 0;
    for (int i = 0; i < w; ++i) woff += wsum[i];
    int ex = (inc - local) + woff + blockSums[blockIdx.x];
    int4 rs;
    rs.x = ex;
    rs.y = rs.x + v.x;
    rs.z = rs.y + v.y;
    rs.w = rs.z + v.z;
    float4 nm;
    nm.x = rsqrtf(fmaxf((float)v.x, 1.0f));
    nm.y = rsqrtf(fmaxf((float)v.y, 1.0f));
    nm.z = rsqrtf(fmaxf((float)v.z, 1.0f));
    nm.w = rsqrtf(fmaxf((float)v.w, 1.0f));
    if (base + 3 < N) {
        *(int4*)(row_start + base) = rs;
        *(int4*)(cursor + base) = rs;
        *(float4*)(norm + base) = nm;
    } else {
        if (base + 0 < N) { row_start[base + 0] = rs.x; cursor[base + 0] = rs.x; norm[base + 0] = nm.x; }
        if (base + 1 < N) { row_start[base + 1] = rs.y; cursor[base + 1] = rs.y; norm[base + 1] = nm.y; }
        if (base + 2 < N) { row_start[base + 2] = rs.z; cursor[base + 2] = rs.z; norm[base + 2] = nm.z; }
    }
    if (blockIdx.x == 0 && tid == 0) row_start[N] = E;
}

// 1 edge/thread; u16 payload (requires N <= 65536): half the scatter footprint
__global__ __launch_bounds__(256) void binning_kernel(
    const int* __restrict__ src, const int* __restrict__ dst,
    int* __restrict__ cursor, unsigned short* __restrict__ sorted16, int E) {
    int e = blockIdx.x * blockDim.x + threadIdx.x;
    if (e < E) {
        int d = dst[e];
        int s = src[e];
        int p = atomicAdd(&cursor[d], 1);
        sorted16[p] = (unsigned short)s;
    }
}

// xs = bf16(x * norm[row])  (reads float4, writes ushort4 = 8B/lane)
__global__ void scale_kernel(const float* __restrict__ x, const float* __restrict__ norm,
                             unsigned short* __restrict__ xsb, int N) {
    int idx = blockIdx.x * blockDim.x + threadIdx.x;
    int total = N * (D / 4);
    if (idx >= total) return;
    int row = idx >> 5;  // D/4 == 32
    float nrm = norm[row];
    float4 v = ((const float4*)x)[idx];
    ushort4 o;
    o.x = f2bf(v.x * nrm);
    o.y = f2bf(v.y * nrm);
    o.z = f2bf(v.z * nrm);
    o.w = f2bf(v.w * nrm);
    ((ushort4*)xsb)[idx] = o;
}

__device__ __forceinline__ void addbf4(float4& a, ushort4 u) {
    a.x += bf2f(u.x);
    a.y += bf2f(u.y);
    a.z += bf2f(u.z);
    a.w += bf2f(u.w);
}

// wave per destination node; bf16 gather (256B/row), fp32 accum; 2 rows in
// flight via lane-halves, 8 outstanding 8B loads/lane; outputs pre-split bf16
__global__ __launch_bounds__(256) void aggregate_kernel(
    const unsigned short* __restrict__ xsb, const unsigned short* __restrict__ sorted16,
    const int* __restrict__ row_start, const float* __restrict__ norm,
    unsigned short* __restrict__ h2hi, unsigned short* __restrict__ h2lo, int N) {
    int wave = (int)((blockIdx.x * blockDim.x + threadIdx.x) >> 6);
    int lane = threadIdx.x & 63;
    if (wave >= N) return;
    int s = row_start[wave];
    int t = row_start[wave + 1];
    int c4 = (lane & 31) << 2;   // element column (4 bf16 per lane)
    int half = lane >> 5;        // which edge of the pair
    float4 acc = make_float4(0.f, 0.f, 0.f, 0.f);
    for (int base = s; base < t; base += 64) {
        int cnt = min(64, t - base);
        int my = (lane < cnt) ? (int)sorted16[base + lane] : 0;
        int j = 0;
        for (; j + 15 < cnt; j += 16) {  // 8 outstanding 8B loads per lane
            int i0 = __shfl(my, j + 0 + half, 64);
            int i1 = __shfl(my, j + 2 + half, 64);
            int i2 = __shfl(my, j + 4 + half, 64);
            int i3 = __shfl(my, j + 6 + half, 64);
            int i4 = __shfl(my, j + 8 + half, 64);
            int i5 = __shfl(my, j + 10 + half, 64);
            int i6 = __shfl(my, j + 12 + half, 64);
            int i7 = __shfl(my, j + 14 + half, 64);
            ushort4 u0 = *(const ushort4*)(xsb + (size_t)i0 * D + c4);
            ushort4 u1 = *(const ushort4*)(xsb + (size_t)i1 * D + c4);
            ushort4 u2 = *(const ushort4*)(xsb + (size_t)i2 * D + c4);
            ushort4 u3 = *(const ushort4*)(xsb + (size_t)i3 * D + c4);
            ushort4 u4 = *(const ushort4*)(xsb + (size_t)i4 * D + c4);
            ushort4 u5 = *(const ushort4*)(xsb + (size_t)i5 * D + c4);
            ushort4 u6 = *(const ushort4*)(xsb + (size_t)i6 * D + c4);
            ushort4 u7 = *(const ushort4*)(xsb + (size_t)i7 * D + c4);
            addbf4(acc, u0); addbf4(acc, u1); addbf4(acc, u2); addbf4(acc, u3);
            addbf4(acc, u4); addbf4(acc, u5); addbf4(acc, u6); addbf4(acc, u7);
        }
        for (; j + 1 < cnt; j += 2) {
            int i0 = __shfl(my, j + half, 64);
            ushort4 u0 = *(const ushort4*)(xsb + (size_t)i0 * D + c4);
            addbf4(acc, u0);
        }
        if (j < cnt) {  // odd leftover edge: half 0 only
            int i0 = __shfl(my, j, 64);
            if (half == 0) {
                ushort4 u0 = *(const ushort4*)(xsb + (size_t)i0 * D + c4);
                addbf4(acc, u0);
            }
        }
    }
    // combine the two halves
    acc.x += __shfl_xor(acc.x, 32, 64);
    acc.y += __shfl_xor(acc.y, 32, 64);
    acc.z += __shfl_xor(acc.z, 32, 64);
    acc.w += __shfl_xor(acc.w, 32, 64);
    if (half == 0) {
        float nrm = norm[wave];
        float o[4] = {acc.x * nrm, acc.y * nrm, acc.z * nrm, acc.w * nrm};
        ushort4 hv, lv;
        unsigned short* hp = (unsigned short*)&hv;
        unsigned short* lp = (unsigned short*)&lv;
        #pragma unroll
        for (int q = 0; q < 4; ++q) {
            unsigned short h = f2bf(o[q]);
            float r = o[q] - bf2f(h);
            hp[q] = h;
            lp[q] = f2bf(r);
        }
        *(ushort4*)(h2hi + (size_t)wave * D + c4) = hv;
        *(ushort4*)(h2lo + (size_t)wave * D + c4) = lv;
    }
}

// ---------------- MFMA MLP (2-way split) ----------------
// weight prep: split each fp32 into hi/lo bf16
__global__ __launch_bounds__(256) void prep_w_kernel(
    const float* __restrict__ wc, const float* __restrict__ wl,
    unsigned short* __restrict__ w1c, unsigned short* __restrict__ w2c,
    unsigned short* __restrict__ w1l, unsigned short* __restrict__ w2l) {
    int idx = blockIdx.x * 256 + threadIdx.x;  // 0..32767
    const float* src = (idx < 16384) ? wc : wl;
    int j = idx & 16383;
    float x = src[j];
    unsigned short c1 = f2bf(x);
    float r = x - bf2f(c1);
    unsigned short c2 = f2bf(r);
    if (idx < 16384) { w1c[j] = c1; w2c[j] = c2; }
    else             { w1l[j] = c1; w2l[j] = c2; }
}

// LDS tiles: bf16 [64 rows][128], 16B slots swizzled: slot' = slot ^ (row&7)
__device__ __forceinline__ void layer_bf(
    const unsigned short* shi, const unsigned short* slo,
    const unsigned short* __restrict__ w1, const unsigned short* __restrict__ w2,
    const float* __restrict__ bias,
    f32x4 acc[2][4], int wr0, int wc0, int lm, int lg) {
    #pragma unroll
    for (int mt = 0; mt < 2; ++mt)
        #pragma unroll
        for (int nt = 0; nt < 4; ++nt) {
            float b = bias[wc0 + nt * 16 + lm];
            acc[mt][nt] = (f32x4){b, b, b, b};
        }
    #pragma unroll
    for (int k0 = 0; k0 < 128; k0 += 32) {
        short8 ahi[2], alo[2];
        #pragma unroll
        for (int mt = 0; mt < 2; ++mt) {
            int row = wr0 + mt * 16 + lm;
            int slot = (k0 >> 3) + lg;
            int off = row * 128 + (((slot) ^ (row & 7)) << 3);
            ahi[mt] = *(const short8*)(shi + off);
            alo[mt] = *(const short8*)(slo + off);
        }
        #pragma unroll
        for (int nt = 0; nt < 4; ++nt) {
            int widx = (wc0 + nt * 16 + lm) * 128 + k0 + lg * 8;
            short8 bhi = *(const short8*)(w1 + widx);
            short8 blo = *(const short8*)(w2 + widx);
            #pragma unroll
            for (int mt = 0; mt < 2; ++mt) {
                f32x4 c = acc[mt][nt];
                c = __builtin_amdgcn_mfma_f32_16x16x32_bf16(ahi[mt], blo, c, 0, 0, 0);
                c = __builtin_amdgcn_mfma_f32_16x16x32_bf16(alo[mt], bhi, c, 0, 0, 0);
                c = __builtin_amdgcn_mfma_f32_16x16x32_bf16(ahi[mt], bhi, c, 0, 0, 0);
                acc[mt][nt] = c;
            }
        }
    }
}

// relu + split into swizzled bf16 LDS (C layout: col=lane&15, row=(lane>>4)*4+reg)
__device__ __forceinline__ void store_bf(
    unsigned short* shi, unsigned short* slo,
    f32x4 acc[2][4], int wr0, int wc0, int lm, int lg) {
    #pragma unroll
    for (int mt = 0; mt < 2; ++mt)
        #pragma unroll
        for (int nt = 0; nt < 4; ++nt)
            #pragma unroll
            for (int j = 0; j < 4; ++j) {
                int row = wr0 + mt * 16 + lg * 4 + j;
                int col = wc0 + nt * 16 + lm;
                float v = fmaxf(acc[mt][nt][j], 0.0f);
                unsigned short h = f2bf(v);
                float r = v - bf2f(h);
                int off = row * 128 + (((col >> 3) ^ (row & 7)) << 3) + (col & 7);
                shi[off] = h;
                slo[off] = f2bf(r);
            }
}

__global__ __launch_bounds__(256, 2) void mlp_mfma_kernel(
    const unsigned short* __restrict__ h2hi, const unsigned short* __restrict__ h2lo,
    const unsigned short* __restrict__ w1c, const unsigned short* __restrict__ w2c,
    const float* __restrict__ bc,
    const unsigned short* __restrict__ w1l, const unsigned short* __restrict__ w2l,
    const float* __restrict__ bl,
    float* __restrict__ out, int N) {
    __shared__ unsigned short shi[64 * 128];  // 16 KB
    __shared__ unsigned short slo[64 * 128];  // 16 KB
    int tid = threadIdx.x;
    int row0 = blockIdx.x * 64;

    // stage pre-split h2 (coalesced 16B global loads -> swizzled LDS slots)
    #pragma unroll
    for (int i = 0; i < 4; ++i) {
        int f = i * 256 + tid;            // slot id 0..1023
        int r = f >> 4, sl = f & 15;
        int grow = row0 + r;
        short8 vh = (short8){0,0,0,0,0,0,0,0};
        short8 vl = (short8){0,0,0,0,0,0,0,0};
        if (grow < N) {
            vh = *(const short8*)(h2hi + (size_t)grow * D + sl * 8);
            vl = *(const short8*)(h2lo + (size_t)grow * D + sl * 8);
        }
        int off = r * 128 + ((sl ^ (r & 7)) << 3);
        *(short8*)(shi + off) = vh;
        *(short8*)(slo + off) = vl;
    }
    __syncthreads();

    int w = tid >> 6, lane = tid & 63;
    int lm = lane & 15, lg = lane >> 4;
    int wr0 = (w >> 1) * 32, wc0 = (w & 1) * 64;

    f32x4 acc[2][4];

    layer_bf(shi, slo, w1c, w2c, bc, acc, wr0, wc0, lm, lg);
    __syncthreads();                   // all reads of tiles done
    store_bf(shi, slo, acc, wr0, wc0, lm, lg);
    __syncthreads();

    layer_bf(shi, slo, w1l, w2l, bl, acc, wr0, wc0, lm, lg);

    // direct relu + store to global (64B-granular coalescing per 16-lane group)
    #pragma unroll
    for (int mt = 0; mt < 2; ++mt)
        #pragma unroll
        for (int j = 0; j < 4; ++j) {
            int row = row0 + wr0 + mt * 16 + lg * 4 + j;
            if (row < N) {
                #pragma unroll
                for (int nt = 0; nt < 4; ++nt)
                    out[(size_t)row * D + wc0 + nt * 16 + lm] = fmaxf(acc[mt][nt][j], 0.0f);
            }
        }
}

extern "C" void kernel_launch(void* const* d_in, const int* in_sizes, int n_in,
                              void* d_out, int out_size, void* d_ws, size_t ws_size,
                              hipStream_t stream) {
    const float* x      = (const float*)d_in[0];
    const int*   src    = (const int*)d_in[1];
    const int*   dst    = (const int*)d_in[2];
    const float* wc     = (const float*)d_in[3];
    const float* bc     = (const float*)d_in[4];
    const float* wl     = (const float*)d_in[5];
    const float* bl     = (const float*)d_in[6];
    float* out = (float*)d_out;

    int N = in_sizes[0] / D;
    int E = in_sizes[1];

    // workspace carve-up (256B aligned)
    size_t off = 0;
    auto carve = [&](size_t bytes) -> void* {
        void* p = (char*)d_ws + off;
        off += (bytes + 255) & ~(size_t)255;
        return p;
    };
    unsigned short* xsb       = (unsigned short*)carve((size_t)N * D * 2);
    unsigned short* h2hi      = (unsigned short*)carve((size_t)N * D * 2);
    unsigned short* h2lo      = (unsigned short*)carve((size_t)N * D * 2);
    int*            deg       = (int*)carve((size_t)N * 4);
    int*            row_start = (int*)carve((size_t)(N + 1) * 4);
    int*            cursor    = (int*)carve((size_t)N * 4);
    float*          norm      = (float*)carve((size_t)N * 4);
    int*            blockSums = (int*)carve(1024 * 4);
    unsigned short* sorted16  = (unsigned short*)carve((size_t)E * 2);
    unsigned short* w1c = (unsigned short*)carve(16384 * 2);
    unsigned short* w2c = (unsigned short*)carve(16384 * 2);
    unsigned short* w1l = (unsigned short*)carve(16384 * 2);
    unsigned short* w2l = (unsigned short*)carve(16384 * 2);
    (void)ws_size;

    hipMemsetAsync(deg, 0, (size_t)N * 4, stream);

    int nScanBlocks = (N + SCAN_TILE - 1) / SCAN_TILE;

    prep_w_kernel<<<128, 256, 0, stream>>>(wc, wl, w1c, w2c, w1l, w2l);
    degree_kernel<<<(E + 255) / 256, 256, 0, stream>>>(dst, deg, E);
    scan_partial_kernel<<<nScanBlocks, 256, 0, stream>>>(deg, blockSums, N);
    scan_blocksums_kernel<<<1, 256, 0, stream>>>(blockSums, nScanBlocks);
    scan_final_kernel<<<nScanBlocks, 256, 0, stream>>>(deg, blockSums, row_start, cursor, norm, N, E);
    binning_kernel<<<(E + 255) / 256, 256, 0, stream>>>(src, dst, cursor, sorted16, E);
    {
        int total = N * (D / 4);
        scale_kernel<<<(total + 255) / 256, 256, 0, stream>>>(x, norm, xsb, N);
    }
    aggregate_kernel<<<(N + 3) / 4, 256, 0, stream>>>(xsb, sorted16, row_start, norm, h2hi, h2lo, N);
    mlp_mfma_kernel<<<(N + 63) / 64, 256, 0, stream>>>(h2hi, h2lo, w1c, w2c, bc, w1l, w2l, bl, out, N);
}